// Round 2
// baseline (3446.209 us; speedup 1.0000x reference)
//
#include <hip/hip_runtime.h>

// CommAgent fully-fused pipeline for MI355X (gfx950), bf16 MFMA throughout.
// ROWS=65536, INPUT=512, H=256, NA=32, 4 comm steps, N_ACTIONS=16.
//
// Round-2 fix: gru computed per 32-row half (r->z->n->epilogue) so the live
// register set fits without scratch spills (round-1 spilled ~9KB/thread,
// 2.4 GB of scratch writes). Weights are re-read 2x per GRU (L2-resident).

typedef __attribute__((ext_vector_type(8))) short frag8;   // 8 bf16 (4 VGPRs)
typedef __attribute__((ext_vector_type(4))) float facc4;   // MFMA C/D

__device__ __forceinline__ unsigned short f2bf(float f){
    unsigned u = __builtin_bit_cast(unsigned, f);
    u += 0x7fffu + ((u >> 16) & 1u);            // RNE
    return (unsigned short)(u >> 16);
}
__device__ __forceinline__ float bf2f(unsigned short h){
    unsigned u = ((unsigned)h) << 16;
    return __builtin_bit_cast(float, u);
}
__device__ __forceinline__ unsigned pk2(float a, float b){
    return (unsigned)f2bf(a) | ((unsigned)f2bf(b) << 16);
}
__device__ __forceinline__ float sigm(float x){ return 1.0f / (1.0f + __expf(-x)); }
__device__ __forceinline__ float tanh_(float x){ return 2.0f / (1.0f + __expf(-2.0f*x)) - 1.0f; }

__device__ __forceinline__ facc4 mfma16(frag8 a, frag8 b, facc4 c){
    return __builtin_amdgcn_mfma_f32_16x16x32_bf16(a, b, c, 0, 0, 0);
}
__device__ __forceinline__ void zacc(facc4* p, int n){
    #pragma unroll
    for (int i = 0; i < 16; ++i) { if (i < n) p[i] = (facc4){0.f,0.f,0.f,0.f}; }
}
// XOR-swizzled LDS index (16B-chunk granularity), ld=256 shorts
__device__ __forceinline__ int swz(int row, int col, int ld){
    return row*ld + ((((col >> 3) ^ (row & 7)) << 3) | (col & 7));
}

// acc[NMB][4] += A_lds(rows mb0*16..) @ W[nbase+ncols, K]^T ; wave owns n-tiles 4w..4w+3
template<int NMB>
__device__ __forceinline__ void gemm_bt(facc4 acc[NMB][4],
    const unsigned short* Al, const int ld, const int mb0,
    const unsigned short* __restrict__ W, const int nbase, const int K, const int wK)
{
    const int lane = threadIdx.x & 63;
    const int wave = threadIdx.x >> 6;
    const int r16  = lane & 15;
    const int q8   = (lane >> 4) << 3;
    int rowbase[NMB], rx[NMB];
    #pragma unroll
    for (int mb = 0; mb < NMB; ++mb){
        int row = (mb0 + mb)*16 + r16;
        rowbase[mb] = row * ld;
        rx[mb] = row & 7;
    }
    const unsigned short* wbase = W + (size_t)(nbase + wave*64 + r16) * wK + q8;
    for (int k0 = 0; k0 < K; k0 += 32){
        const int c8 = (k0 + q8) >> 3;
        frag8 a[NMB];
        #pragma unroll
        for (int mb = 0; mb < NMB; ++mb)
            a[mb] = *(const frag8*)(Al + rowbase[mb] + ((c8 ^ rx[mb]) << 3));
        #pragma unroll
        for (int tt = 0; tt < 4; ++tt){
            frag8 b = *(const frag8*)(wbase + tt*16*wK + k0);
            #pragma unroll
            for (int mb = 0; mb < NMB; ++mb)
                acc[mb][tt] = mfma16(a[mb], b, acc[mb][tt]);
        }
    }
}

// stage 64 rows x 256 cols of f32 (row stride sld) -> swizzled bf16 LDS (ld=256)
__device__ __forceinline__ void stage_f32s(unsigned short* dst, const float* src, int sld){
    int t = threadIdx.x;
    #pragma unroll
    for (int it = 0; it < 8; ++it){
        int idx = it*256 + t;                  // 2048 chunks of 8 shorts
        int row = idx >> 5, ch = idx & 31;
        const float4* s = (const float4*)(src + (size_t)row*sld + (ch << 3));
        float4 a = s[0], b = s[1];
        uint4 o; o.x = pk2(a.x,a.y); o.y = pk2(a.z,a.w); o.z = pk2(b.x,b.y); o.w = pk2(b.z,b.w);
        *(uint4*)(dst + row*256 + ((ch ^ (row & 7)) << 3)) = o;
    }
}

// ---- weight f32->bf16 conversion (segments packed contiguously in ws) ----
__global__ void k_prep(const float* __restrict__ s0, const float* __restrict__ s1,
                       const float* __restrict__ s2, const float* __restrict__ s3,
                       const float* __restrict__ s4, const float* __restrict__ s5,
                       unsigned short* __restrict__ dst)
{
    int idx = (blockIdx.x*256 + threadIdx.x) * 4;   // 921600 elems total
    const float* src;
    if      (idx < 131072) src = s0 + idx;
    else if (idx < 327680) src = s1 + (idx - 131072);
    else if (idx < 524288) src = s2 + (idx - 327680);
    else if (idx < 720896) src = s3 + (idx - 524288);
    else if (idx < 917504) src = s4 + (idx - 720896);
    else                   src = s5 + (idx - 917504);
    float4 v = *(const float4*)src;
    uint2 o; o.x = pk2(v.x, v.y); o.y = pk2(v.z, v.w);
    *(uint2*)(dst + idx) = o;
}

// ---- GRU, one 32-row half (m-blocks mbh*2, mbh*2+1), full r->z->n pipeline.
// gi from giA, gh from ghA, h = (1-z)*n + z*ghA. Result packed into hpk;
// optionally writes f32 h to out32 (hrnn).
template<bool WRITE_F32>
__device__ __forceinline__ void gru_half(const int mbh,
    const unsigned short* giA, const unsigned short* ghA,   // LDS, ld=256 swizzled
    const unsigned short* __restrict__ Wih, const unsigned short* __restrict__ Whh,
    const float* __restrict__ bih, const float* __restrict__ bhh,
    int base, float* __restrict__ out32, unsigned (&hpk)[2][4][2])
{
    const int lane = threadIdx.x & 63, wave = threadIdx.x >> 6;
    const int r16 = lane & 15, q4 = (lane >> 4) << 2;
    const int mb0 = mbh*2;
    unsigned rp[2][4][2], zp[2][4][2];
    // phase r
    {
        facc4 acc[2][4];
        zacc(&acc[0][0], 8);
        gemm_bt<2>(acc, giA, 256, mb0, Wih, 0, 256, 256);
        gemm_bt<2>(acc, ghA, 256, mb0, Whh, 0, 256, 256);
        #pragma unroll
        for (int tt = 0; tt < 4; ++tt){
            int col = wave*64 + tt*16 + r16;
            float bs = bih[col] + bhh[col];
            #pragma unroll
            for (int m2 = 0; m2 < 2; ++m2){
                rp[m2][tt][0] = pk2(sigm(acc[m2][tt][0]+bs), sigm(acc[m2][tt][1]+bs));
                rp[m2][tt][1] = pk2(sigm(acc[m2][tt][2]+bs), sigm(acc[m2][tt][3]+bs));
            }
        }
    }
    // phase z
    {
        facc4 acc[2][4];
        zacc(&acc[0][0], 8);
        gemm_bt<2>(acc, giA, 256, mb0, Wih, 256, 256, 256);
        gemm_bt<2>(acc, ghA, 256, mb0, Whh, 256, 256, 256);
        #pragma unroll
        for (int tt = 0; tt < 4; ++tt){
            int col = wave*64 + tt*16 + r16;
            float bs = bih[256+col] + bhh[256+col];
            #pragma unroll
            for (int m2 = 0; m2 < 2; ++m2){
                zp[m2][tt][0] = pk2(sigm(acc[m2][tt][0]+bs), sigm(acc[m2][tt][1]+bs));
                zp[m2][tt][1] = pk2(sigm(acc[m2][tt][2]+bs), sigm(acc[m2][tt][3]+bs));
            }
        }
    }
    // phase n + epilogue
    {
        facc4 ai[2][4], ah[2][4];
        zacc(&ai[0][0], 8);
        zacc(&ah[0][0], 8);
        gemm_bt<2>(ai, giA, 256, mb0, Wih, 512, 256, 256);
        gemm_bt<2>(ah, ghA, 256, mb0, Whh, 512, 256, 256);
        #pragma unroll
        for (int tt = 0; tt < 4; ++tt){
            int col = wave*64 + tt*16 + r16;
            float bi = bih[512+col], bh = bhh[512+col];
            #pragma unroll
            for (int m2 = 0; m2 < 2; ++m2){
                float hv[4];
                #pragma unroll
                for (int k = 0; k < 4; ++k){
                    int rloc = (mb0 + m2)*16 + q4 + k;
                    float iv = ai[m2][tt][k] + bi;
                    float hvv = ah[m2][tt][k] + bh;
                    float r = bf2f((unsigned short)(rp[m2][tt][k>>1] >> ((k&1)*16)));
                    float z = bf2f((unsigned short)(zp[m2][tt][k>>1] >> ((k&1)*16)));
                    float n = tanh_(iv + r*hvv);
                    float hp = bf2f(ghA[swz(rloc, col, 256)]);
                    float h = (1.f - z)*n + z*hp;
                    if (WRITE_F32) out32[(size_t)(base + rloc)*256 + col] = h;
                    hv[k] = h;
                }
                hpk[m2][tt][0] = pk2(hv[0], hv[1]);
                hpk[m2][tt][1] = pk2(hv[2], hv[3]);
            }
        }
    }
}

// write one packed half (32 rows) into swizzled LDS tile
__device__ __forceinline__ void write_h_half(unsigned short* Al, int mbh,
                                             const unsigned (&hpk)[2][4][2]){
    const int lane = threadIdx.x & 63, wave = threadIdx.x >> 6;
    const int r16 = lane & 15, q4 = (lane >> 4) << 2;
    #pragma unroll
    for (int m2 = 0; m2 < 2; ++m2){
        #pragma unroll
        for (int tt = 0; tt < 4; ++tt){
            int col = wave*64 + tt*16 + r16;
            #pragma unroll
            for (int k = 0; k < 4; ++k){
                int rloc = (mbh*2 + m2)*16 + q4 + k;
                Al[swz(rloc, col, 256)] =
                    (unsigned short)(hpk[m2][tt][k>>1] >> ((k&1)*16));
            }
        }
    }
}

// c = (NB @ h) * invn, per 32-agent group; h in Hl (swizzled), out to Cl (swizzled)
__device__ __forceinline__ void comm_c(const unsigned short* Hl, unsigned short* Cl,
                                       const unsigned short* NBl, const float* invl)
{
    const int lane = threadIdx.x & 63, wave = threadIdx.x >> 6;
    const int r16 = lane & 15, q8 = (lane >> 4) << 3, q4 = (lane >> 4) << 2;
    facc4 acc[4][4];
    zacc(&acc[0][0], 16);
    frag8 a[4];
    #pragma unroll
    for (int mb = 0; mb < 4; ++mb)
        a[mb] = *(const frag8*)(NBl + (mb*16 + r16)*40 + q8);
    #pragma unroll
    for (int tt = 0; tt < 4; ++tt){
        int col = wave*64 + tt*16 + r16;
        int cc = col >> 3, c7 = col & 7;
        frag8 b0, b1;
        #pragma unroll
        for (int j = 0; j < 8; ++j){
            int k0r = q8 + j;          // group 0 rows 0..31
            int k1r = 32 + q8 + j;     // group 1 rows 32..63
            b0[j] = (short)Hl[k0r*256 + (((cc ^ (k0r & 7)) << 3) | c7)];
            b1[j] = (short)Hl[k1r*256 + (((cc ^ (k1r & 7)) << 3) | c7)];
        }
        acc[0][tt] = mfma16(a[0], b0, acc[0][tt]);
        acc[1][tt] = mfma16(a[1], b0, acc[1][tt]);
        acc[2][tt] = mfma16(a[2], b1, acc[2][tt]);
        acc[3][tt] = mfma16(a[3], b1, acc[3][tt]);
    }
    #pragma unroll
    for (int mb = 0; mb < 4; ++mb){
        #pragma unroll
        for (int k = 0; k < 4; ++k){
            int rloc = mb*16 + q4 + k;
            float inv = invl[rloc];
            #pragma unroll
            for (int tt = 0; tt < 4; ++tt){
                int col = wave*64 + tt*16 + r16;
                Cl[swz(rloc, col, 256)] = f2bf(acc[mb][tt][k] * inv);
            }
        }
    }
}

// ---- the whole pipeline, 64 rows (2 agent groups) per block ----
__global__ __launch_bounds__(256,2) void k_fused(
    const float* __restrict__ inputs, const float* __restrict__ h0,
    const unsigned short* __restrict__ W1c, const float* __restrict__ b1,
    const unsigned short* __restrict__ rWih, const unsigned short* __restrict__ rWhh,
    const float* __restrict__ rbih, const float* __restrict__ rbhh,
    const unsigned short* __restrict__ cWih, const unsigned short* __restrict__ cWhh,
    const float* __restrict__ cbih, const float* __restrict__ cbhh,
    const unsigned short* __restrict__ W2c, const float* __restrict__ b2,
    float* __restrict__ qout, float* __restrict__ hrnn)
{
    __shared__ unsigned short A[64*256];     // 32 KB: X, then h
    __shared__ unsigned short B[64*256];     // 32 KB: input halves, h0, then C
    __shared__ unsigned short NBl[64*40];    // 5 KB (padded ld=40 vs bank conflicts)
    __shared__ float invl[64];
    const int base = blockIdx.x * 64;
    const int lane = threadIdx.x & 63, wave = threadIdx.x >> 6;
    const int r16 = lane & 15, q8 = (lane >> 4) << 3, q4 = (lane >> 4) << 2;

    // ================= phase X: x = relu(inp @ W1^T + b1) -> A =================
    {
        facc4 acc[4][4];
        zacc(&acc[0][0], 16);
        // K-half 1 (input cols 0..255)
        stage_f32s(B, inputs + (size_t)base*512, 512);
        __syncthreads();
        gemm_bt<4>(acc, B, 256, 0, W1c, 0, 256, 512);
        __syncthreads();                            // all reads of B done
        // K-half 2 (input cols 256..511)
        stage_f32s(B, inputs + (size_t)base*512 + 256, 512);
        __syncthreads();
        // neighbor extraction: global cols 260+8k -> local col 4+8k -> chunk k, sub 4
        if (threadIdx.x < 64){
            int row = threadIdx.x;
            int gr = base + row;
            int i = gr & 31;
            int rx = row & 7;
            unsigned short* nbrow = NBl + row*40;
            float s = 0.f;
            nbrow[i] = 0;
            #pragma unroll
            for (int k = 0; k < 31; ++k){
                unsigned short v = B[row*256 + (((k ^ rx) << 3) | 4)];
                s += bf2f(v);
                nbrow[k + (k >= i)] = v;
            }
            invl[row] = 1.0f / s;
        }
        gemm_bt<4>(acc, B, 256, 0, W1c + 256, 0, 256, 512);
        // write X -> A (A not read by anyone yet)
        #pragma unroll
        for (int tt = 0; tt < 4; ++tt){
            int col = wave*64 + tt*16 + r16;
            float bias = b1[col];
            #pragma unroll
            for (int mb = 0; mb < 4; ++mb){
                #pragma unroll
                for (int k = 0; k < 4; ++k){
                    float v = fmaxf(acc[mb][tt][k] + bias, 0.f);
                    A[swz(mb*16 + q4 + k, col, 256)] = f2bf(v);
                }
            }
        }
    }
    __syncthreads();                // X in A; all reads of B done

    // ================= rnn GRU: h1 = GRU(X, h0) =================
    stage_f32s(B, h0 + (size_t)base*256, 256);
    __syncthreads();
    {
        unsigned hp0[2][4][2], hp1[2][4][2];
        gru_half<true>(0, A, B, rWih, rWhh, rbih, rbhh, base, hrnn, hp0);
        gru_half<true>(1, A, B, rWih, rWhh, rbih, rbhh, base, hrnn, hp1);
        __syncthreads();            // all reads of A (X) and B (h0) done
        write_h_half(A, 0, hp0);    // h1 -> A
        write_h_half(A, 1, hp1);
    }
    __syncthreads();

    // ================= 4 comm steps, fully in LDS =================
    #pragma unroll 1
    for (int step = 0; step < 4; ++step){
        comm_c(A, B, NBl, invl);    // C -> B
        __syncthreads();
        unsigned hp0[2][4][2], hp1[2][4][2];
        gru_half<false>(0, A, B, cWih, cWhh, cbih, cbhh, base, nullptr, hp0);
        gru_half<false>(1, A, B, cWih, cWhh, cbih, cbhh, base, nullptr, hp1);
        __syncthreads();            // all reads of A (h) and B (c) done
        write_h_half(A, 0, hp0);    // h' -> A
        write_h_half(A, 1, hp1);
        __syncthreads();
    }

    // ================= q = h @ W2^T + b2 (N=16, one n-tile) =================
    {
        facc4 qa = (facc4){0.f,0.f,0.f,0.f};
        int rowl = wave*16 + r16;
        const int rb = rowl*256, rx = rowl & 7;
        const unsigned short* brow = W2c + (size_t)r16*256 + q8;
        #pragma unroll
        for (int k0 = 0; k0 < 256; k0 += 32){
            int c8 = (k0 + q8) >> 3;
            frag8 af = *(const frag8*)(A + rb + ((c8 ^ rx) << 3));
            frag8 bf = *(const frag8*)(brow + k0);
            qa = mfma16(af, bf, qa);
        }
        float bias = b2[r16];
        #pragma unroll
        for (int k = 0; k < 4; ++k)
            qout[(size_t)(base + wave*16 + q4 + k)*16 + r16] = qa[k] + bias;
    }
}

extern "C" void kernel_launch(void* const* d_in, const int* in_sizes, int n_in,
                              void* d_out, int out_size, void* d_ws, size_t ws_size,
                              hipStream_t stream)
{
    const float* inputs = (const float*)d_in[0];
    const float* h0     = (const float*)d_in[1];
    const float* W1     = (const float*)d_in[2];
    const float* b1     = (const float*)d_in[3];
    const float* rWih   = (const float*)d_in[4];
    const float* rWhh   = (const float*)d_in[5];
    const float* rbih   = (const float*)d_in[6];
    const float* rbhh   = (const float*)d_in[7];
    const float* cWih   = (const float*)d_in[8];
    const float* cWhh   = (const float*)d_in[9];
    const float* cbih   = (const float*)d_in[10];
    const float* cbhh   = (const float*)d_in[11];
    const float* W2     = (const float*)d_in[12];
    const float* b2     = (const float*)d_in[13];

    float* qout = (float*)d_out;                    // 65536 x 16
    float* hrnn = qout + (size_t)65536*16;          // 65536 x 256

    // ws: bf16 weights only (921600 elems), segments packed contiguously
    unsigned short* wsb   = (unsigned short*)d_ws;
    unsigned short* W1c   = wsb;
    unsigned short* rWihc = wsb + 131072;
    unsigned short* rWhhc = wsb + 327680;
    unsigned short* cWihc = wsb + 524288;
    unsigned short* cWhhc = wsb + 720896;
    unsigned short* W2c   = wsb + 917504;

    dim3 blk(256);
    k_prep <<<900, blk, 0, stream>>>(W1, rWih, rWhh, cWih, cWhh, W2, wsb);
    k_fused<<<1024, blk, 0, stream>>>(inputs, h0, W1c, b1,
                                      rWihc, rWhhc, rbih, rbhh,
                                      cWihc, cWhhc, cbih, cbhh,
                                      W2c, b2, qout, hrnn);
}

// Round 4
// 3270.287 us; speedup vs baseline: 1.0538x; 1.0538x over previous
//
#include <hip/hip_runtime.h>

// CommAgent fully-fused pipeline for MI355X (gfx950), bf16 MFMA throughout.
// ROWS=65536, INPUT=512, H=256, NA=32, 4 comm steps, N_ACTIONS=16.
//
// Round-4 (= round-3 theory, compile-fixed): kill scratch spills (r1/r2 wrote
// ~2.3 GB of scratch; VGPR stuck at 128 while LDS caps occupancy at 2
// waves/SIMD anyway).
//  (a) amdgpu_waves_per_eu(2,2): allocator may use 256 VGPRs (LDS already
//      limits to 2 blocks/CU, so this costs nothing).
//  (b) n-phase split into column halves (ai/ah 32 regs not 64); each GRU
//      row-half written to LDS before the next starts (halves touch
//      disjoint A rows), so hp0/hp1 never live together.
//  (c) non-temporal loads/stores for the pure streams (inputs, h0, hrnn, q)
//      so they stop evicting L2-resident weights.
//      (fix: ext_vector_type float4 for __builtin_nontemporal_load)

typedef __attribute__((ext_vector_type(8))) short frag8;   // 8 bf16 (4 VGPRs)
typedef __attribute__((ext_vector_type(4))) float facc4;   // MFMA C/D
typedef __attribute__((ext_vector_type(4))) float f32x4;   // NT-loadable float4

__device__ __forceinline__ unsigned short f2bf(float f){
    unsigned u = __builtin_bit_cast(unsigned, f);
    u += 0x7fffu + ((u >> 16) & 1u);            // RNE
    return (unsigned short)(u >> 16);
}
__device__ __forceinline__ float bf2f(unsigned short h){
    unsigned u = ((unsigned)h) << 16;
    return __builtin_bit_cast(float, u);
}
__device__ __forceinline__ unsigned pk2(float a, float b){
    return (unsigned)f2bf(a) | ((unsigned)f2bf(b) << 16);
}
__device__ __forceinline__ float sigm(float x){ return 1.0f / (1.0f + __expf(-x)); }
__device__ __forceinline__ float tanh_(float x){ return 2.0f / (1.0f + __expf(-2.0f*x)) - 1.0f; }

__device__ __forceinline__ facc4 mfma16(frag8 a, frag8 b, facc4 c){
    return __builtin_amdgcn_mfma_f32_16x16x32_bf16(a, b, c, 0, 0, 0);
}
__device__ __forceinline__ void zacc(facc4* p, int n){
    #pragma unroll
    for (int i = 0; i < 16; ++i) { if (i < n) p[i] = (facc4){0.f,0.f,0.f,0.f}; }
}
// XOR-swizzled LDS index (16B-chunk granularity), ld=256 shorts
__device__ __forceinline__ int swz(int row, int col, int ld){
    return row*ld + ((((col >> 3) ^ (row & 7)) << 3) | (col & 7));
}

// acc[NMB][NTT] += A_lds(rows mb0*16..) @ W[nrow0 + NTT*16 rows, K]^T
// nrow0 already includes gate offset + wave*64 (+ tth*32).
template<int NMB, int NTT>
__device__ __forceinline__ void gemm_bt(facc4 (&acc)[NMB][NTT],
    const unsigned short* Al, const int ld, const int mb0,
    const unsigned short* __restrict__ W, const int nrow0, const int K, const int wK)
{
    const int lane = threadIdx.x & 63;
    const int r16  = lane & 15;
    const int q8   = (lane >> 4) << 3;
    int rowbase[NMB], rx[NMB];
    #pragma unroll
    for (int mb = 0; mb < NMB; ++mb){
        int row = (mb0 + mb)*16 + r16;
        rowbase[mb] = row * ld;
        rx[mb] = row & 7;
    }
    const unsigned short* wbase = W + (size_t)(nrow0 + r16) * wK + q8;
    for (int k0 = 0; k0 < K; k0 += 32){
        const int c8 = (k0 + q8) >> 3;
        frag8 a[NMB];
        #pragma unroll
        for (int mb = 0; mb < NMB; ++mb)
            a[mb] = *(const frag8*)(Al + rowbase[mb] + ((c8 ^ rx[mb]) << 3));
        #pragma unroll
        for (int tt = 0; tt < NTT; ++tt){
            frag8 b = *(const frag8*)(wbase + tt*16*wK + k0);
            #pragma unroll
            for (int mb = 0; mb < NMB; ++mb)
                acc[mb][tt] = mfma16(a[mb], b, acc[mb][tt]);
        }
    }
}

// stage 64 rows x 256 cols of f32 (row stride sld) -> swizzled bf16 LDS (ld=256)
// non-temporal loads: pure stream, keep out of L2's way
__device__ __forceinline__ void stage_f32s(unsigned short* dst, const float* src, int sld){
    int t = threadIdx.x;
    #pragma unroll
    for (int it = 0; it < 8; ++it){
        int idx = it*256 + t;                  // 2048 chunks of 8 shorts
        int row = idx >> 5, ch = idx & 31;
        const f32x4* s = (const f32x4*)(src + (size_t)row*sld + (ch << 3));
        f32x4 a = __builtin_nontemporal_load(s);
        f32x4 b = __builtin_nontemporal_load(s + 1);
        uint4 o; o.x = pk2(a.x,a.y); o.y = pk2(a.z,a.w); o.z = pk2(b.x,b.y); o.w = pk2(b.z,b.w);
        *(uint4*)(dst + row*256 + ((ch ^ (row & 7)) << 3)) = o;
    }
}

// ---- weight f32->bf16 conversion (segments packed contiguously in ws) ----
__global__ void k_prep(const float* __restrict__ s0, const float* __restrict__ s1,
                       const float* __restrict__ s2, const float* __restrict__ s3,
                       const float* __restrict__ s4, const float* __restrict__ s5,
                       unsigned short* __restrict__ dst)
{
    int idx = (blockIdx.x*256 + threadIdx.x) * 4;   // 921600 elems total
    const float* src;
    if      (idx < 131072) src = s0 + idx;
    else if (idx < 327680) src = s1 + (idx - 131072);
    else if (idx < 524288) src = s2 + (idx - 327680);
    else if (idx < 720896) src = s3 + (idx - 524288);
    else if (idx < 917504) src = s4 + (idx - 720896);
    else                   src = s5 + (idx - 917504);
    float4 v = *(const float4*)src;
    uint2 o; o.x = pk2(v.x, v.y); o.y = pk2(v.z, v.w);
    *(uint2*)(dst + idx) = o;
}

// ---- GRU, one 32-row half (m-blocks mb0=mbh*2, +1), r->z->n pipeline.
// n-phase additionally split over column halves to bound live registers.
template<bool WRITE_F32>
__device__ __forceinline__ void gru_half(const int mbh,
    const unsigned short* giA, const unsigned short* ghA,   // LDS, ld=256 swizzled
    const unsigned short* __restrict__ Wih, const unsigned short* __restrict__ Whh,
    const float* __restrict__ bih, const float* __restrict__ bhh,
    int base, float* __restrict__ out32, unsigned (&hpk)[2][4][2])
{
    const int lane = threadIdx.x & 63, wv = threadIdx.x >> 6;
    const int r16 = lane & 15, q4 = (lane >> 4) << 2;
    const int mb0 = mbh*2;
    unsigned rp[2][4][2], zp[2][4][2];
    // phase r
    {
        facc4 acc[2][4];
        zacc(&acc[0][0], 8);
        gemm_bt<2,4>(acc, giA, 256, mb0, Wih, wv*64, 256, 256);
        gemm_bt<2,4>(acc, ghA, 256, mb0, Whh, wv*64, 256, 256);
        #pragma unroll
        for (int tt = 0; tt < 4; ++tt){
            int col = wv*64 + tt*16 + r16;
            float bs = bih[col] + bhh[col];
            #pragma unroll
            for (int m2 = 0; m2 < 2; ++m2){
                rp[m2][tt][0] = pk2(sigm(acc[m2][tt][0]+bs), sigm(acc[m2][tt][1]+bs));
                rp[m2][tt][1] = pk2(sigm(acc[m2][tt][2]+bs), sigm(acc[m2][tt][3]+bs));
            }
        }
    }
    // phase z
    {
        facc4 acc[2][4];
        zacc(&acc[0][0], 8);
        gemm_bt<2,4>(acc, giA, 256, mb0, Wih, 256 + wv*64, 256, 256);
        gemm_bt<2,4>(acc, ghA, 256, mb0, Whh, 256 + wv*64, 256, 256);
        #pragma unroll
        for (int tt = 0; tt < 4; ++tt){
            int col = wv*64 + tt*16 + r16;
            float bs = bih[256+col] + bhh[256+col];
            #pragma unroll
            for (int m2 = 0; m2 < 2; ++m2){
                zp[m2][tt][0] = pk2(sigm(acc[m2][tt][0]+bs), sigm(acc[m2][tt][1]+bs));
                zp[m2][tt][1] = pk2(sigm(acc[m2][tt][2]+bs), sigm(acc[m2][tt][3]+bs));
            }
        }
    }
    // phase n + epilogue, column halves (tth): 32 cols each
    #pragma unroll
    for (int tth = 0; tth < 2; ++tth){
        facc4 ai[2][2], ah[2][2];
        zacc(&ai[0][0], 4);
        zacc(&ah[0][0], 4);
        gemm_bt<2,2>(ai, giA, 256, mb0, Wih, 512 + wv*64 + tth*32, 256, 256);
        gemm_bt<2,2>(ah, ghA, 256, mb0, Whh, 512 + wv*64 + tth*32, 256, 256);
        #pragma unroll
        for (int tt = 0; tt < 2; ++tt){
            int tfull = tth*2 + tt;
            int col = wv*64 + tth*32 + tt*16 + r16;
            float bi = bih[512+col], bh = bhh[512+col];
            #pragma unroll
            for (int m2 = 0; m2 < 2; ++m2){
                float hv[4];
                #pragma unroll
                for (int k = 0; k < 4; ++k){
                    int rloc = (mb0 + m2)*16 + q4 + k;
                    float iv = ai[m2][tt][k] + bi;
                    float hvv = ah[m2][tt][k] + bh;
                    float r = bf2f((unsigned short)(rp[m2][tfull][k>>1] >> ((k&1)*16)));
                    float z = bf2f((unsigned short)(zp[m2][tfull][k>>1] >> ((k&1)*16)));
                    float n = tanh_(iv + r*hvv);
                    float hp = bf2f(ghA[swz(rloc, col, 256)]);
                    float h = (1.f - z)*n + z*hp;
                    if (WRITE_F32)
                        __builtin_nontemporal_store(h, &out32[(size_t)(base + rloc)*256 + col]);
                    hv[k] = h;
                }
                hpk[m2][tfull][0] = pk2(hv[0], hv[1]);
                hpk[m2][tfull][1] = pk2(hv[2], hv[3]);
            }
        }
    }
}

// write one packed half (32 rows) into swizzled LDS tile
__device__ __forceinline__ void write_h_half(unsigned short* Al, int mbh,
                                             const unsigned (&hpk)[2][4][2]){
    const int lane = threadIdx.x & 63, wv = threadIdx.x >> 6;
    const int r16 = lane & 15, q4 = (lane >> 4) << 2;
    #pragma unroll
    for (int m2 = 0; m2 < 2; ++m2){
        #pragma unroll
        for (int tt = 0; tt < 4; ++tt){
            int col = wv*64 + tt*16 + r16;
            #pragma unroll
            for (int k = 0; k < 4; ++k){
                int rloc = (mbh*2 + m2)*16 + q4 + k;
                Al[swz(rloc, col, 256)] =
                    (unsigned short)(hpk[m2][tt][k>>1] >> ((k&1)*16));
            }
        }
    }
}

// c = (NB @ h) * invn, per 32-agent group; h in Hl (swizzled), out to Cl (swizzled)
__device__ __forceinline__ void comm_c(const unsigned short* Hl, unsigned short* Cl,
                                       const unsigned short* NBl, const float* invl)
{
    const int lane = threadIdx.x & 63, wv = threadIdx.x >> 6;
    const int r16 = lane & 15, q8 = (lane >> 4) << 3, q4 = (lane >> 4) << 2;
    facc4 acc[4][4];
    zacc(&acc[0][0], 16);
    frag8 a[4];
    #pragma unroll
    for (int mb = 0; mb < 4; ++mb)
        a[mb] = *(const frag8*)(NBl + (mb*16 + r16)*40 + q8);
    #pragma unroll
    for (int tt = 0; tt < 4; ++tt){
        int col = wv*64 + tt*16 + r16;
        int cc = col >> 3, c7 = col & 7;
        frag8 b0, b1;
        #pragma unroll
        for (int j = 0; j < 8; ++j){
            int k0r = q8 + j;          // group 0 rows 0..31
            int k1r = 32 + q8 + j;     // group 1 rows 32..63
            b0[j] = (short)Hl[k0r*256 + (((cc ^ (k0r & 7)) << 3) | c7)];
            b1[j] = (short)Hl[k1r*256 + (((cc ^ (k1r & 7)) << 3) | c7)];
        }
        acc[0][tt] = mfma16(a[0], b0, acc[0][tt]);
        acc[1][tt] = mfma16(a[1], b0, acc[1][tt]);
        acc[2][tt] = mfma16(a[2], b1, acc[2][tt]);
        acc[3][tt] = mfma16(a[3], b1, acc[3][tt]);
    }
    #pragma unroll
    for (int mb = 0; mb < 4; ++mb){
        #pragma unroll
        for (int k = 0; k < 4; ++k){
            int rloc = mb*16 + q4 + k;
            float inv = invl[rloc];
            #pragma unroll
            for (int tt = 0; tt < 4; ++tt){
                int col = wv*64 + tt*16 + r16;
                Cl[swz(rloc, col, 256)] = f2bf(acc[mb][tt][k] * inv);
            }
        }
    }
}

// ---- the whole pipeline, 64 rows (2 agent groups) per block ----
__global__ __launch_bounds__(256)
__attribute__((amdgpu_waves_per_eu(2, 2)))
void k_fused(
    const float* __restrict__ inputs, const float* __restrict__ h0,
    const unsigned short* __restrict__ W1c, const float* __restrict__ b1,
    const unsigned short* __restrict__ rWih, const unsigned short* __restrict__ rWhh,
    const float* __restrict__ rbih, const float* __restrict__ rbhh,
    const unsigned short* __restrict__ cWih, const unsigned short* __restrict__ cWhh,
    const float* __restrict__ cbih, const float* __restrict__ cbhh,
    const unsigned short* __restrict__ W2c, const float* __restrict__ b2,
    float* __restrict__ qout, float* __restrict__ hrnn)
{
    __shared__ unsigned short A[64*256];     // 32 KB: X, then h
    __shared__ unsigned short B[64*256];     // 32 KB: input halves, h0, then C
    __shared__ unsigned short NBl[64*40];    // 5 KB (padded ld=40 vs bank conflicts)
    __shared__ float invl[64];
    const int base = blockIdx.x * 64;
    const int lane = threadIdx.x & 63, wv = threadIdx.x >> 6;
    const int r16 = lane & 15, q8 = (lane >> 4) << 3, q4 = (lane >> 4) << 2;

    // ================= phase X: x = relu(inp @ W1^T + b1) -> A =================
    {
        facc4 acc[4][4];
        zacc(&acc[0][0], 16);
        // K-half 1 (input cols 0..255)
        stage_f32s(B, inputs + (size_t)base*512, 512);
        __syncthreads();
        gemm_bt<4,4>(acc, B, 256, 0, W1c, wv*64, 256, 512);
        __syncthreads();                            // all reads of B done
        // K-half 2 (input cols 256..511)
        stage_f32s(B, inputs + (size_t)base*512 + 256, 512);
        __syncthreads();
        // neighbor extraction: global cols 260+8k -> local col 4+8k -> chunk k, sub 4
        if (threadIdx.x < 64){
            int row = threadIdx.x;
            int gr = base + row;
            int i = gr & 31;
            int rx = row & 7;
            unsigned short* nbrow = NBl + row*40;
            float s = 0.f;
            nbrow[i] = 0;
            #pragma unroll
            for (int k = 0; k < 31; ++k){
                unsigned short v = B[row*256 + (((k ^ rx) << 3) | 4)];
                s += bf2f(v);
                nbrow[k + (k >= i)] = v;
            }
            invl[row] = 1.0f / s;
        }
        gemm_bt<4,4>(acc, B, 256, 0, W1c + 256, wv*64, 256, 512);
        // write X -> A (A not read by anyone yet)
        #pragma unroll
        for (int tt = 0; tt < 4; ++tt){
            int col = wv*64 + tt*16 + r16;
            float bias = b1[col];
            #pragma unroll
            for (int mb = 0; mb < 4; ++mb){
                #pragma unroll
                for (int k = 0; k < 4; ++k){
                    float v = fmaxf(acc[mb][tt][k] + bias, 0.f);
                    A[swz(mb*16 + q4 + k, col, 256)] = f2bf(v);
                }
            }
        }
    }
    __syncthreads();                // X in A; all reads of B done

    // ================= rnn GRU: h1 = GRU(X, h0) =================
    stage_f32s(B, h0 + (size_t)base*256, 256);
    __syncthreads();
    {
        unsigned hp[2][4][2];
        gru_half<true>(0, A, B, rWih, rWhh, rbih, rbhh, base, hrnn, hp);
        __syncthreads();            // all waves done reading A/B rows 0..31
        write_h_half(A, 0, hp);     // h1 rows 0..31 -> A (half 1 reads rows 32..63 only)
        gru_half<true>(1, A, B, rWih, rWhh, rbih, rbhh, base, hrnn, hp);
        __syncthreads();
        write_h_half(A, 1, hp);
    }
    __syncthreads();

    // ================= 4 comm steps, fully in LDS =================
    #pragma unroll 1
    for (int step = 0; step < 4; ++step){
        comm_c(A, B, NBl, invl);    // C -> B
        __syncthreads();
        unsigned hp[2][4][2];
        gru_half<false>(0, A, B, cWih, cWhh, cbih, cbhh, base, nullptr, hp);
        __syncthreads();
        write_h_half(A, 0, hp);
        gru_half<false>(1, A, B, cWih, cWhh, cbih, cbhh, base, nullptr, hp);
        __syncthreads();
        write_h_half(A, 1, hp);
        __syncthreads();
    }

    // ================= q = h @ W2^T + b2 (N=16, one n-tile) =================
    {
        facc4 qa = (facc4){0.f,0.f,0.f,0.f};
        int rowl = wv*16 + r16;
        const int rb = rowl*256, rx = rowl & 7;
        const unsigned short* brow = W2c + (size_t)r16*256 + q8;
        #pragma unroll
        for (int k0 = 0; k0 < 256; k0 += 32){
            int c8 = (k0 + q8) >> 3;
            frag8 af = *(const frag8*)(A + rb + ((c8 ^ rx) << 3));
            frag8 bf = *(const frag8*)(brow + k0);
            qa = mfma16(af, bf, qa);
        }
        float bias = b2[r16];
        #pragma unroll
        for (int k = 0; k < 4; ++k)
            __builtin_nontemporal_store(qa[k] + bias,
                &qout[(size_t)(base + wv*16 + q4 + k)*16 + r16]);
    }
}

extern "C" void kernel_launch(void* const* d_in, const int* in_sizes, int n_in,
                              void* d_out, int out_size, void* d_ws, size_t ws_size,
                              hipStream_t stream)
{
    const float* inputs = (const float*)d_in[0];
    const float* h0     = (const float*)d_in[1];
    const float* W1     = (const float*)d_in[2];
    const float* b1     = (const float*)d_in[3];
    const float* rWih   = (const float*)d_in[4];
    const float* rWhh   = (const float*)d_in[5];
    const float* rbih   = (const float*)d_in[6];
    const float* rbhh   = (const float*)d_in[7];
    const float* cWih   = (const float*)d_in[8];
    const float* cWhh   = (const float*)d_in[9];
    const float* cbih   = (const float*)d_in[10];
    const float* cbhh   = (const float*)d_in[11];
    const float* W2     = (const float*)d_in[12];
    const float* b2     = (const float*)d_in[13];

    float* qout = (float*)d_out;                    // 65536 x 16
    float* hrnn = qout + (size_t)65536*16;          // 65536 x 256

    // ws: bf16 weights only (921600 elems), segments packed contiguously
    unsigned short* wsb   = (unsigned short*)d_ws;
    unsigned short* W1c   = wsb;
    unsigned short* rWihc = wsb + 131072;
    unsigned short* rWhhc = wsb + 327680;
    unsigned short* cWihc = wsb + 524288;
    unsigned short* cWhhc = wsb + 720896;
    unsigned short* W2c   = wsb + 917504;

    dim3 blk(256);
    k_prep <<<900, blk, 0, stream>>>(W1, rWih, rWhh, cWih, cWhh, W2, wsb);
    k_fused<<<1024, blk, 0, stream>>>(inputs, h0, W1c, b1,
                                      rWihc, rWhhc, rbih, rbhh,
                                      cWihc, cWhhc, cbih, cbhh,
                                      W2c, b2, qout, hrnn);
}

// Round 5
// 2758.609 us; speedup vs baseline: 1.2493x; 1.1855x over previous
//
#include <hip/hip_runtime.h>

// CommAgent fully-fused pipeline for MI355X (gfx950), bf16 MFMA throughout.
// ROWS=65536, INPUT=512, H=256, NA=32, 4 comm steps, N_ACTIONS=16.
//
// Round-5: 512-thread blocks (8 waves x 32 output cols each). Halves every
// per-thread register array vs the 256-thread variant: worst-phase live set
// ~88 VGPRs under a hard 128 cap (__launch_bounds__(512,4)) -> provably no
// spill headroom issues. GRU phase order r -> z -> n, with the epilogue
// fused into the n phase (no packed-h buffer at all). Weights read 4 passes
// per GRU (r 1x, z 1x, n 2x). LDS 70 KB -> 2 blocks/CU (4 waves/SIMD).
// NT loads on streams kept; NT stores reverted (suspected write amplifier).

typedef __attribute__((ext_vector_type(8))) short frag8;   // 8 bf16 (4 VGPRs)
typedef __attribute__((ext_vector_type(4))) float facc4;   // MFMA C/D
typedef __attribute__((ext_vector_type(4))) float f32x4;   // NT-loadable float4

__device__ __forceinline__ unsigned short f2bf(float f){
    unsigned u = __builtin_bit_cast(unsigned, f);
    u += 0x7fffu + ((u >> 16) & 1u);            // RNE
    return (unsigned short)(u >> 16);
}
__device__ __forceinline__ float bf2f(unsigned short h){
    unsigned u = ((unsigned)h) << 16;
    return __builtin_bit_cast(float, u);
}
__device__ __forceinline__ unsigned pk2(float a, float b){
    return (unsigned)f2bf(a) | ((unsigned)f2bf(b) << 16);
}
__device__ __forceinline__ float sigm(float x){ return 1.0f / (1.0f + __expf(-x)); }
__device__ __forceinline__ float tanh_(float x){ return 2.0f / (1.0f + __expf(-2.0f*x)) - 1.0f; }

__device__ __forceinline__ facc4 mfma16(frag8 a, frag8 b, facc4 c){
    return __builtin_amdgcn_mfma_f32_16x16x32_bf16(a, b, c, 0, 0, 0);
}
__device__ __forceinline__ void zacc(facc4* p, int n){
    #pragma unroll
    for (int i = 0; i < 16; ++i) { if (i < n) p[i] = (facc4){0.f,0.f,0.f,0.f}; }
}
// XOR-swizzled LDS index (16B-chunk granularity), ld=256 shorts
__device__ __forceinline__ int swz(int row, int col, int ld){
    return row*ld + ((((col >> 3) ^ (row & 7)) << 3) | (col & 7));
}

// acc[NMB][NTT] += A_lds(rows mb0*16..) @ W[nrow0 + tt*16 rows, K]^T
// nrow0 already includes gate offset + wv*32.
template<int NMB, int NTT>
__device__ __forceinline__ void gemm_bt(facc4 (&acc)[NMB][NTT],
    const unsigned short* Al, const int ld, const int mb0,
    const unsigned short* __restrict__ W, const int nrow0, const int K, const int wK)
{
    const int lane = threadIdx.x & 63;
    const int r16  = lane & 15;
    const int q8   = (lane >> 4) << 3;
    int rowbase[NMB], rx[NMB];
    #pragma unroll
    for (int mb = 0; mb < NMB; ++mb){
        int row = (mb0 + mb)*16 + r16;
        rowbase[mb] = row * ld;
        rx[mb] = row & 7;
    }
    const unsigned short* wbase = W + (size_t)(nrow0 + r16) * wK + q8;
    for (int k0 = 0; k0 < K; k0 += 32){
        const int c8 = (k0 + q8) >> 3;
        frag8 a[NMB];
        #pragma unroll
        for (int mb = 0; mb < NMB; ++mb)
            a[mb] = *(const frag8*)(Al + rowbase[mb] + ((c8 ^ rx[mb]) << 3));
        #pragma unroll
        for (int tt = 0; tt < NTT; ++tt){
            frag8 b = *(const frag8*)(wbase + tt*16*wK + k0);
            #pragma unroll
            for (int mb = 0; mb < NMB; ++mb)
                acc[mb][tt] = mfma16(a[mb], b, acc[mb][tt]);
        }
    }
}

// stage 64 rows x 256 cols of f32 (row stride sld) -> swizzled bf16 LDS (ld=256)
// 512 threads; non-temporal loads (pure stream)
__device__ __forceinline__ void stage_f32s(unsigned short* dst, const float* src, int sld){
    int t = threadIdx.x;
    #pragma unroll
    for (int it = 0; it < 4; ++it){
        int idx = it*512 + t;                  // 2048 chunks of 8 shorts
        int row = idx >> 5, ch = idx & 31;
        const f32x4* s = (const f32x4*)(src + (size_t)row*sld + (ch << 3));
        f32x4 a = __builtin_nontemporal_load(s);
        f32x4 b = __builtin_nontemporal_load(s + 1);
        uint4 o; o.x = pk2(a.x,a.y); o.y = pk2(a.z,a.w); o.z = pk2(b.x,b.y); o.w = pk2(b.z,b.w);
        *(uint4*)(dst + row*256 + ((ch ^ (row & 7)) << 3)) = o;
    }
}

// ---- weight f32->bf16 conversion (segments packed contiguously in ws) ----
__global__ void k_prep(const float* __restrict__ s0, const float* __restrict__ s1,
                       const float* __restrict__ s2, const float* __restrict__ s3,
                       const float* __restrict__ s4, const float* __restrict__ s5,
                       unsigned short* __restrict__ dst)
{
    int idx = (blockIdx.x*256 + threadIdx.x) * 4;   // 921600 elems total
    const float* src;
    if      (idx < 131072) src = s0 + idx;
    else if (idx < 327680) src = s1 + (idx - 131072);
    else if (idx < 524288) src = s2 + (idx - 327680);
    else if (idx < 720896) src = s3 + (idx - 524288);
    else if (idx < 917504) src = s4 + (idx - 720896);
    else                   src = s5 + (idx - 917504);
    float4 v = *(const float4*)src;
    uint2 o; o.x = pk2(v.x, v.y); o.y = pk2(v.z, v.w);
    *(uint2*)(dst + idx) = o;
}

// ---- GRU for the full 64-row tile (512 threads, 8 waves x 32 cols).
// gi input read from A (and h written back into A); gh input read from B.
// Phase order: r -> z -> n(+fused epilogue, by 32-row halves).
// h = (1-z)*n + z*B   (B is the "hidden" operand per reference gru_cell)
template<bool WRITE_F32>
__device__ __forceinline__ void gru(
    unsigned short* A, const unsigned short* B,      // LDS, ld=256 swizzled
    const unsigned short* __restrict__ Wih, const unsigned short* __restrict__ Whh,
    const float* __restrict__ bih, const float* __restrict__ bhh,
    int base, float* __restrict__ out32)
{
    const int lane = threadIdx.x & 63, wv = threadIdx.x >> 6;
    const int r16 = lane & 15, q4 = (lane >> 4) << 2;
    unsigned rp[4][2][2], zp[4][2][2];
    // phase r
    {
        facc4 acc[4][2];
        zacc(&acc[0][0], 8);
        gemm_bt<4,2>(acc, A, 256, 0, Wih, wv*32, 256, 256);
        gemm_bt<4,2>(acc, B, 256, 0, Whh, wv*32, 256, 256);
        #pragma unroll
        for (int tt = 0; tt < 2; ++tt){
            int col = wv*32 + tt*16 + r16;
            float bs = bih[col] + bhh[col];
            #pragma unroll
            for (int mb = 0; mb < 4; ++mb){
                rp[mb][tt][0] = pk2(sigm(acc[mb][tt][0]+bs), sigm(acc[mb][tt][1]+bs));
                rp[mb][tt][1] = pk2(sigm(acc[mb][tt][2]+bs), sigm(acc[mb][tt][3]+bs));
            }
        }
    }
    // phase z
    {
        facc4 acc[4][2];
        zacc(&acc[0][0], 8);
        gemm_bt<4,2>(acc, A, 256, 0, Wih, 256 + wv*32, 256, 256);
        gemm_bt<4,2>(acc, B, 256, 0, Whh, 256 + wv*32, 256, 256);
        #pragma unroll
        for (int tt = 0; tt < 2; ++tt){
            int col = wv*32 + tt*16 + r16;
            float bs = bih[256+col] + bhh[256+col];
            #pragma unroll
            for (int mb = 0; mb < 4; ++mb){
                zp[mb][tt][0] = pk2(sigm(acc[mb][tt][0]+bs), sigm(acc[mb][tt][1]+bs));
                zp[mb][tt][1] = pk2(sigm(acc[mb][tt][2]+bs), sigm(acc[mb][tt][3]+bs));
            }
        }
    }
    // phase n + fused epilogue, by 32-row halves.
    // Barrier before each half's writes: all waves' reads of those A rows
    // (r/z gemms read all rows; n-h0 reads 0..31) are complete; half-1 gemms
    // read rows 32..63 only, disjoint from half-0's writes.
    #pragma unroll
    for (int mbh = 0; mbh < 2; ++mbh){
        facc4 ai[2][2], ah[2][2];
        zacc(&ai[0][0], 4);
        zacc(&ah[0][0], 4);
        gemm_bt<2,2>(ai, A, 256, mbh*2, Wih, 512 + wv*32, 256, 256);
        gemm_bt<2,2>(ah, B, 256, mbh*2, Whh, 512 + wv*32, 256, 256);
        __syncthreads();
        #pragma unroll
        for (int tt = 0; tt < 2; ++tt){
            int col = wv*32 + tt*16 + r16;
            float bi = bih[512+col], bh2 = bhh[512+col];
            #pragma unroll
            for (int m2 = 0; m2 < 2; ++m2){
                int mb = mbh*2 + m2;
                #pragma unroll
                for (int k = 0; k < 4; ++k){
                    int rloc = mb*16 + q4 + k;
                    float iv = ai[m2][tt][k] + bi;
                    float hv = ah[m2][tt][k] + bh2;
                    float r = bf2f((unsigned short)(rp[mb][tt][k>>1] >> ((k&1)*16)));
                    float z = bf2f((unsigned short)(zp[mb][tt][k>>1] >> ((k&1)*16)));
                    float n = tanh_(iv + r*hv);
                    float hprev = bf2f(B[swz(rloc, col, 256)]);
                    float h = (1.f - z)*n + z*hprev;
                    if (WRITE_F32) out32[(size_t)(base + rloc)*256 + col] = h;
                    A[swz(rloc, col, 256)] = f2bf(h);
                }
            }
        }
    }
}

// c = (NB @ h) * invn, per 32-agent group; h in Hl (swizzled), out to Cl (swizzled)
__device__ __forceinline__ void comm_c(const unsigned short* Hl, unsigned short* Cl,
                                       const unsigned short* NBl, const float* invl)
{
    const int lane = threadIdx.x & 63, wv = threadIdx.x >> 6;
    const int r16 = lane & 15, q8 = (lane >> 4) << 3, q4 = (lane >> 4) << 2;
    facc4 acc[4][2];
    zacc(&acc[0][0], 8);
    frag8 a[4];
    #pragma unroll
    for (int mb = 0; mb < 4; ++mb)
        a[mb] = *(const frag8*)(NBl + (mb*16 + r16)*40 + q8);
    #pragma unroll
    for (int tt = 0; tt < 2; ++tt){
        int col = wv*32 + tt*16 + r16;
        int cc = col >> 3, c7 = col & 7;
        frag8 b0, b1;
        #pragma unroll
        for (int j = 0; j < 8; ++j){
            int k0r = q8 + j;          // group 0 rows 0..31
            int k1r = 32 + q8 + j;     // group 1 rows 32..63
            b0[j] = (short)Hl[k0r*256 + (((cc ^ (k0r & 7)) << 3) | c7)];
            b1[j] = (short)Hl[k1r*256 + (((cc ^ (k1r & 7)) << 3) | c7)];
        }
        acc[0][tt] = mfma16(a[0], b0, acc[0][tt]);
        acc[1][tt] = mfma16(a[1], b0, acc[1][tt]);
        acc[2][tt] = mfma16(a[2], b1, acc[2][tt]);
        acc[3][tt] = mfma16(a[3], b1, acc[3][tt]);
    }
    #pragma unroll
    for (int mb = 0; mb < 4; ++mb){
        #pragma unroll
        for (int k = 0; k < 4; ++k){
            int rloc = mb*16 + q4 + k;
            float inv = invl[rloc];
            #pragma unroll
            for (int tt = 0; tt < 2; ++tt){
                int col = wv*32 + tt*16 + r16;
                Cl[swz(rloc, col, 256)] = f2bf(acc[mb][tt][k] * inv);
            }
        }
    }
}

// ---- the whole pipeline, 64 rows (2 agent groups) per block, 512 threads ----
__global__ __launch_bounds__(512, 4) void k_fused(
    const float* __restrict__ inputs, const float* __restrict__ h0,
    const unsigned short* __restrict__ W1c, const float* __restrict__ b1,
    const unsigned short* __restrict__ rWih, const unsigned short* __restrict__ rWhh,
    const float* __restrict__ rbih, const float* __restrict__ rbhh,
    const unsigned short* __restrict__ cWih, const unsigned short* __restrict__ cWhh,
    const float* __restrict__ cbih, const float* __restrict__ cbhh,
    const unsigned short* __restrict__ W2c, const float* __restrict__ b2,
    float* __restrict__ qout, float* __restrict__ hrnn)
{
    __shared__ unsigned short A[64*256];     // 32 KB: X, then h
    __shared__ unsigned short B[64*256];     // 32 KB: input halves, h0, then C
    __shared__ unsigned short NBl[64*40];    // 5 KB (padded ld=40 vs bank conflicts)
    __shared__ float invl[64];
    const int base = blockIdx.x * 64;
    const int lane = threadIdx.x & 63, wv = threadIdx.x >> 6;
    const int r16 = lane & 15, q8 = (lane >> 4) << 3, q4 = (lane >> 4) << 2;

    // ================= phase X: x = relu(inp @ W1^T + b1) -> A =================
    {
        facc4 acc[4][2];
        zacc(&acc[0][0], 8);
        // K-half 1 (input cols 0..255)
        stage_f32s(B, inputs + (size_t)base*512, 512);
        __syncthreads();
        gemm_bt<4,2>(acc, B, 256, 0, W1c, wv*32, 256, 512);
        __syncthreads();                            // all reads of B done
        // K-half 2 (input cols 256..511)
        stage_f32s(B, inputs + (size_t)base*512 + 256, 512);
        __syncthreads();
        // neighbor extraction: global cols 260+8k -> local col 4+8k -> chunk k, sub 4
        if (threadIdx.x < 64){
            int row = threadIdx.x;
            int gr = base + row;
            int i = gr & 31;
            int rx = row & 7;
            unsigned short* nbrow = NBl + row*40;
            float s = 0.f;
            nbrow[i] = 0;
            #pragma unroll
            for (int k = 0; k < 31; ++k){
                unsigned short v = B[row*256 + (((k ^ rx) << 3) | 4)];
                s += bf2f(v);
                nbrow[k + (k >= i)] = v;
            }
            invl[row] = 1.0f / s;
        }
        gemm_bt<4,2>(acc, B, 256, 0, W1c + 256, wv*32, 256, 512);
        // write X -> A (A not read by anyone yet)
        #pragma unroll
        for (int tt = 0; tt < 2; ++tt){
            int col = wv*32 + tt*16 + r16;
            float bias = b1[col];
            #pragma unroll
            for (int mb = 0; mb < 4; ++mb){
                #pragma unroll
                for (int k = 0; k < 4; ++k){
                    float v = fmaxf(acc[mb][tt][k] + bias, 0.f);
                    A[swz(mb*16 + q4 + k, col, 256)] = f2bf(v);
                }
            }
        }
    }
    __syncthreads();                // X in A; all reads of B done

    // ================= rnn GRU: h1 = GRU(X, h0) -> A =================
    stage_f32s(B, h0 + (size_t)base*256, 256);
    __syncthreads();
    gru<true>(A, B, rWih, rWhh, rbih, rbhh, base, hrnn);
    __syncthreads();

    // ================= 4 comm steps, fully in LDS =================
    #pragma unroll 1
    for (int step = 0; step < 4; ++step){
        comm_c(A, B, NBl, invl);    // reads A, writes c -> B
        __syncthreads();
        gru<false>(A, B, cWih, cWhh, cbih, cbhh, base, nullptr);
        __syncthreads();
    }

    // ================= q = h @ W2^T + b2 (N=16, one n-tile) =================
    if (wv < 4){
        facc4 qa = (facc4){0.f,0.f,0.f,0.f};
        int rowl = wv*16 + r16;
        const int rb = rowl*256, rx = rowl & 7;
        const unsigned short* brow = W2c + (size_t)r16*256 + q8;
        #pragma unroll
        for (int k0 = 0; k0 < 256; k0 += 32){
            int c8 = (k0 + q8) >> 3;
            frag8 af = *(const frag8*)(A + rb + ((c8 ^ rx) << 3));
            frag8 bf = *(const frag8*)(brow + k0);
            qa = mfma16(af, bf, qa);
        }
        float bias = b2[r16];
        #pragma unroll
        for (int k = 0; k < 4; ++k)
            qout[(size_t)(base + wv*16 + q4 + k)*16 + r16] = qa[k] + bias;
    }
}

extern "C" void kernel_launch(void* const* d_in, const int* in_sizes, int n_in,
                              void* d_out, int out_size, void* d_ws, size_t ws_size,
                              hipStream_t stream)
{
    const float* inputs = (const float*)d_in[0];
    const float* h0     = (const float*)d_in[1];
    const float* W1     = (const float*)d_in[2];
    const float* b1     = (const float*)d_in[3];
    const float* rWih   = (const float*)d_in[4];
    const float* rWhh   = (const float*)d_in[5];
    const float* rbih   = (const float*)d_in[6];
    const float* rbhh   = (const float*)d_in[7];
    const float* cWih   = (const float*)d_in[8];
    const float* cWhh   = (const float*)d_in[9];
    const float* cbih   = (const float*)d_in[10];
    const float* cbhh   = (const float*)d_in[11];
    const float* W2     = (const float*)d_in[12];
    const float* b2     = (const float*)d_in[13];

    float* qout = (float*)d_out;                    // 65536 x 16
    float* hrnn = qout + (size_t)65536*16;          // 65536 x 256

    // ws: bf16 weights only (921600 elems), segments packed contiguously
    unsigned short* wsb   = (unsigned short*)d_ws;
    unsigned short* W1c   = wsb;
    unsigned short* rWihc = wsb + 131072;
    unsigned short* rWhhc = wsb + 327680;
    unsigned short* cWihc = wsb + 524288;
    unsigned short* cWhhc = wsb + 720896;
    unsigned short* W2c   = wsb + 917504;

    k_prep <<<900, dim3(256), 0, stream>>>(W1, rWih, rWhh, cWih, cWhh, W2, wsb);
    k_fused<<<1024, dim3(512), 0, stream>>>(inputs, h0, W1c, b1,
                                            rWihc, rWhhc, rbih, rbhh,
                                            cWihc, cWhhc, cbih, cbhh,
                                            W2c, b2, qout, hrnn);
}

// Round 6
// 2157.647 us; speedup vs baseline: 1.5972x; 1.2785x over previous
//
#include <hip/hip_runtime.h>

// CommAgent fully-fused pipeline for MI355X (gfx950), bf16 MFMA throughout.
// ROWS=65536, INPUT=512, H=256, NA=32, 4 comm steps, N_ACTIONS=16.
//
// Round-6: identical structure to round 5 (512 threads, 8 waves x 32 cols,
// fused n-phase epilogue). ONE change: __launch_bounds__(512, 1).
// Round 5's (512,4) pinned VGPR to 64 -> 2.9 GB scratch spills (the
// monotone VGPR-cap vs WRITE_SIZE correlation across r2/r4/r5 proves the
// excess writes are spill traffic). Worst-phase live set is ~110-120 VGPRs;
// with no forced minimum the allocator can just take them. LDS (71 KB,
// 2 blocks/CU = 4 waves/SIMD) remains the occupancy limiter if VGPR<=128.

typedef __attribute__((ext_vector_type(8))) short frag8;   // 8 bf16 (4 VGPRs)
typedef __attribute__((ext_vector_type(4))) float facc4;   // MFMA C/D
typedef __attribute__((ext_vector_type(4))) float f32x4;   // NT-loadable float4

__device__ __forceinline__ unsigned short f2bf(float f){
    unsigned u = __builtin_bit_cast(unsigned, f);
    u += 0x7fffu + ((u >> 16) & 1u);            // RNE
    return (unsigned short)(u >> 16);
}
__device__ __forceinline__ float bf2f(unsigned short h){
    unsigned u = ((unsigned)h) << 16;
    return __builtin_bit_cast(float, u);
}
__device__ __forceinline__ unsigned pk2(float a, float b){
    return (unsigned)f2bf(a) | ((unsigned)f2bf(b) << 16);
}
__device__ __forceinline__ float sigm(float x){ return 1.0f / (1.0f + __expf(-x)); }
__device__ __forceinline__ float tanh_(float x){ return 2.0f / (1.0f + __expf(-2.0f*x)) - 1.0f; }

__device__ __forceinline__ facc4 mfma16(frag8 a, frag8 b, facc4 c){
    return __builtin_amdgcn_mfma_f32_16x16x32_bf16(a, b, c, 0, 0, 0);
}
__device__ __forceinline__ void zacc(facc4* p, int n){
    #pragma unroll
    for (int i = 0; i < 16; ++i) { if (i < n) p[i] = (facc4){0.f,0.f,0.f,0.f}; }
}
// XOR-swizzled LDS index (16B-chunk granularity), ld=256 shorts
__device__ __forceinline__ int swz(int row, int col, int ld){
    return row*ld + ((((col >> 3) ^ (row & 7)) << 3) | (col & 7));
}

// acc[NMB][NTT] += A_lds(rows mb0*16..) @ W[nrow0 + tt*16 rows, K]^T
// nrow0 already includes gate offset + wv*32.
template<int NMB, int NTT>
__device__ __forceinline__ void gemm_bt(facc4 (&acc)[NMB][NTT],
    const unsigned short* Al, const int ld, const int mb0,
    const unsigned short* __restrict__ W, const int nrow0, const int K, const int wK)
{
    const int lane = threadIdx.x & 63;
    const int r16  = lane & 15;
    const int q8   = (lane >> 4) << 3;
    int rowbase[NMB], rx[NMB];
    #pragma unroll
    for (int mb = 0; mb < NMB; ++mb){
        int row = (mb0 + mb)*16 + r16;
        rowbase[mb] = row * ld;
        rx[mb] = row & 7;
    }
    const unsigned short* wbase = W + (size_t)(nrow0 + r16) * wK + q8;
    for (int k0 = 0; k0 < K; k0 += 32){
        const int c8 = (k0 + q8) >> 3;
        frag8 a[NMB];
        #pragma unroll
        for (int mb = 0; mb < NMB; ++mb)
            a[mb] = *(const frag8*)(Al + rowbase[mb] + ((c8 ^ rx[mb]) << 3));
        #pragma unroll
        for (int tt = 0; tt < NTT; ++tt){
            frag8 b = *(const frag8*)(wbase + tt*16*wK + k0);
            #pragma unroll
            for (int mb = 0; mb < NMB; ++mb)
                acc[mb][tt] = mfma16(a[mb], b, acc[mb][tt]);
        }
    }
}

// stage 64 rows x 256 cols of f32 (row stride sld) -> swizzled bf16 LDS (ld=256)
// 512 threads; non-temporal loads (pure stream)
__device__ __forceinline__ void stage_f32s(unsigned short* dst, const float* src, int sld){
    int t = threadIdx.x;
    #pragma unroll
    for (int it = 0; it < 4; ++it){
        int idx = it*512 + t;                  // 2048 chunks of 8 shorts
        int row = idx >> 5, ch = idx & 31;
        const f32x4* s = (const f32x4*)(src + (size_t)row*sld + (ch << 3));
        f32x4 a = __builtin_nontemporal_load(s);
        f32x4 b = __builtin_nontemporal_load(s + 1);
        uint4 o; o.x = pk2(a.x,a.y); o.y = pk2(a.z,a.w); o.z = pk2(b.x,b.y); o.w = pk2(b.z,b.w);
        *(uint4*)(dst + row*256 + ((ch ^ (row & 7)) << 3)) = o;
    }
}

// ---- weight f32->bf16 conversion (segments packed contiguously in ws) ----
__global__ void k_prep(const float* __restrict__ s0, const float* __restrict__ s1,
                       const float* __restrict__ s2, const float* __restrict__ s3,
                       const float* __restrict__ s4, const float* __restrict__ s5,
                       unsigned short* __restrict__ dst)
{
    int idx = (blockIdx.x*256 + threadIdx.x) * 4;   // 921600 elems total
    const float* src;
    if      (idx < 131072) src = s0 + idx;
    else if (idx < 327680) src = s1 + (idx - 131072);
    else if (idx < 524288) src = s2 + (idx - 327680);
    else if (idx < 720896) src = s3 + (idx - 524288);
    else if (idx < 917504) src = s4 + (idx - 720896);
    else                   src = s5 + (idx - 917504);
    float4 v = *(const float4*)src;
    uint2 o; o.x = pk2(v.x, v.y); o.y = pk2(v.z, v.w);
    *(uint2*)(dst + idx) = o;
}

// ---- GRU for the full 64-row tile (512 threads, 8 waves x 32 cols).
// gi input read from A (and h written back into A); gh input read from B.
// Phase order: r -> z -> n(+fused epilogue, by 32-row halves).
// h = (1-z)*n + z*B   (B is the "hidden" operand per reference gru_cell)
template<bool WRITE_F32>
__device__ __forceinline__ void gru(
    unsigned short* A, const unsigned short* B,      // LDS, ld=256 swizzled
    const unsigned short* __restrict__ Wih, const unsigned short* __restrict__ Whh,
    const float* __restrict__ bih, const float* __restrict__ bhh,
    int base, float* __restrict__ out32)
{
    const int lane = threadIdx.x & 63, wv = threadIdx.x >> 6;
    const int r16 = lane & 15, q4 = (lane >> 4) << 2;
    unsigned rp[4][2][2], zp[4][2][2];
    // phase r
    {
        facc4 acc[4][2];
        zacc(&acc[0][0], 8);
        gemm_bt<4,2>(acc, A, 256, 0, Wih, wv*32, 256, 256);
        gemm_bt<4,2>(acc, B, 256, 0, Whh, wv*32, 256, 256);
        #pragma unroll
        for (int tt = 0; tt < 2; ++tt){
            int col = wv*32 + tt*16 + r16;
            float bs = bih[col] + bhh[col];
            #pragma unroll
            for (int mb = 0; mb < 4; ++mb){
                rp[mb][tt][0] = pk2(sigm(acc[mb][tt][0]+bs), sigm(acc[mb][tt][1]+bs));
                rp[mb][tt][1] = pk2(sigm(acc[mb][tt][2]+bs), sigm(acc[mb][tt][3]+bs));
            }
        }
    }
    // phase z
    {
        facc4 acc[4][2];
        zacc(&acc[0][0], 8);
        gemm_bt<4,2>(acc, A, 256, 0, Wih, 256 + wv*32, 256, 256);
        gemm_bt<4,2>(acc, B, 256, 0, Whh, 256 + wv*32, 256, 256);
        #pragma unroll
        for (int tt = 0; tt < 2; ++tt){
            int col = wv*32 + tt*16 + r16;
            float bs = bih[256+col] + bhh[256+col];
            #pragma unroll
            for (int mb = 0; mb < 4; ++mb){
                zp[mb][tt][0] = pk2(sigm(acc[mb][tt][0]+bs), sigm(acc[mb][tt][1]+bs));
                zp[mb][tt][1] = pk2(sigm(acc[mb][tt][2]+bs), sigm(acc[mb][tt][3]+bs));
            }
        }
    }
    // phase n + fused epilogue, by 32-row halves.
    // Barrier before each half's writes: all waves' reads of those A rows
    // (r/z gemms read all rows) are complete; half-1 gemms read rows 32..63
    // only, disjoint from half-0's writes.
    #pragma unroll
    for (int mbh = 0; mbh < 2; ++mbh){
        facc4 ai[2][2], ah[2][2];
        zacc(&ai[0][0], 4);
        zacc(&ah[0][0], 4);
        gemm_bt<2,2>(ai, A, 256, mbh*2, Wih, 512 + wv*32, 256, 256);
        gemm_bt<2,2>(ah, B, 256, mbh*2, Whh, 512 + wv*32, 256, 256);
        __syncthreads();
        #pragma unroll
        for (int tt = 0; tt < 2; ++tt){
            int col = wv*32 + tt*16 + r16;
            float bi = bih[512+col], bh2 = bhh[512+col];
            #pragma unroll
            for (int m2 = 0; m2 < 2; ++m2){
                int mb = mbh*2 + m2;
                #pragma unroll
                for (int k = 0; k < 4; ++k){
                    int rloc = mb*16 + q4 + k;
                    float iv = ai[m2][tt][k] + bi;
                    float hv = ah[m2][tt][k] + bh2;
                    float r = bf2f((unsigned short)(rp[mb][tt][k>>1] >> ((k&1)*16)));
                    float z = bf2f((unsigned short)(zp[mb][tt][k>>1] >> ((k&1)*16)));
                    float n = tanh_(iv + r*hv);
                    float hprev = bf2f(B[swz(rloc, col, 256)]);
                    float h = (1.f - z)*n + z*hprev;
                    if (WRITE_F32) out32[(size_t)(base + rloc)*256 + col] = h;
                    A[swz(rloc, col, 256)] = f2bf(h);
                }
            }
        }
    }
}

// c = (NB @ h) * invn, per 32-agent group; h in Hl (swizzled), out to Cl (swizzled)
__device__ __forceinline__ void comm_c(const unsigned short* Hl, unsigned short* Cl,
                                       const unsigned short* NBl, const float* invl)
{
    const int lane = threadIdx.x & 63, wv = threadIdx.x >> 6;
    const int r16 = lane & 15, q8 = (lane >> 4) << 3, q4 = (lane >> 4) << 2;
    facc4 acc[4][2];
    zacc(&acc[0][0], 8);
    frag8 a[4];
    #pragma unroll
    for (int mb = 0; mb < 4; ++mb)
        a[mb] = *(const frag8*)(NBl + (mb*16 + r16)*40 + q8);
    #pragma unroll
    for (int tt = 0; tt < 2; ++tt){
        int col = wv*32 + tt*16 + r16;
        int cc = col >> 3, c7 = col & 7;
        frag8 b0, b1;
        #pragma unroll
        for (int j = 0; j < 8; ++j){
            int k0r = q8 + j;          // group 0 rows 0..31
            int k1r = 32 + q8 + j;     // group 1 rows 32..63
            b0[j] = (short)Hl[k0r*256 + (((cc ^ (k0r & 7)) << 3) | c7)];
            b1[j] = (short)Hl[k1r*256 + (((cc ^ (k1r & 7)) << 3) | c7)];
        }
        acc[0][tt] = mfma16(a[0], b0, acc[0][tt]);
        acc[1][tt] = mfma16(a[1], b0, acc[1][tt]);
        acc[2][tt] = mfma16(a[2], b1, acc[2][tt]);
        acc[3][tt] = mfma16(a[3], b1, acc[3][tt]);
    }
    #pragma unroll
    for (int mb = 0; mb < 4; ++mb){
        #pragma unroll
        for (int k = 0; k < 4; ++k){
            int rloc = mb*16 + q4 + k;
            float inv = invl[rloc];
            #pragma unroll
            for (int tt = 0; tt < 2; ++tt){
                int col = wv*32 + tt*16 + r16;
                Cl[swz(rloc, col, 256)] = f2bf(acc[mb][tt][k] * inv);
            }
        }
    }
}

// ---- the whole pipeline, 64 rows (2 agent groups) per block, 512 threads ----
__global__ __launch_bounds__(512, 1) void k_fused(
    const float* __restrict__ inputs, const float* __restrict__ h0,
    const unsigned short* __restrict__ W1c, const float* __restrict__ b1,
    const unsigned short* __restrict__ rWih, const unsigned short* __restrict__ rWhh,
    const float* __restrict__ rbih, const float* __restrict__ rbhh,
    const unsigned short* __restrict__ cWih, const unsigned short* __restrict__ cWhh,
    const float* __restrict__ cbih, const float* __restrict__ cbhh,
    const unsigned short* __restrict__ W2c, const float* __restrict__ b2,
    float* __restrict__ qout, float* __restrict__ hrnn)
{
    __shared__ unsigned short A[64*256];     // 32 KB: X, then h
    __shared__ unsigned short B[64*256];     // 32 KB: input halves, h0, then C
    __shared__ unsigned short NBl[64*40];    // 5 KB (padded ld=40 vs bank conflicts)
    __shared__ float invl[64];
    const int base = blockIdx.x * 64;
    const int lane = threadIdx.x & 63, wv = threadIdx.x >> 6;
    const int r16 = lane & 15, q8 = (lane >> 4) << 3, q4 = (lane >> 4) << 2;

    // ================= phase X: x = relu(inp @ W1^T + b1) -> A =================
    {
        facc4 acc[4][2];
        zacc(&acc[0][0], 8);
        // K-half 1 (input cols 0..255)
        stage_f32s(B, inputs + (size_t)base*512, 512);
        __syncthreads();
        gemm_bt<4,2>(acc, B, 256, 0, W1c, wv*32, 256, 512);
        __syncthreads();                            // all reads of B done
        // K-half 2 (input cols 256..511)
        stage_f32s(B, inputs + (size_t)base*512 + 256, 512);
        __syncthreads();
        // neighbor extraction: global cols 260+8k -> local col 4+8k -> chunk k, sub 4
        if (threadIdx.x < 64){
            int row = threadIdx.x;
            int gr = base + row;
            int i = gr & 31;
            int rx = row & 7;
            unsigned short* nbrow = NBl + row*40;
            float s = 0.f;
            nbrow[i] = 0;
            #pragma unroll
            for (int k = 0; k < 31; ++k){
                unsigned short v = B[row*256 + (((k ^ rx) << 3) | 4)];
                s += bf2f(v);
                nbrow[k + (k >= i)] = v;
            }
            invl[row] = 1.0f / s;
        }
        gemm_bt<4,2>(acc, B, 256, 0, W1c + 256, wv*32, 256, 512);
        // write X -> A (A not read by anyone yet)
        #pragma unroll
        for (int tt = 0; tt < 2; ++tt){
            int col = wv*32 + tt*16 + r16;
            float bias = b1[col];
            #pragma unroll
            for (int mb = 0; mb < 4; ++mb){
                #pragma unroll
                for (int k = 0; k < 4; ++k){
                    float v = fmaxf(acc[mb][tt][k] + bias, 0.f);
                    A[swz(mb*16 + q4 + k, col, 256)] = f2bf(v);
                }
            }
        }
    }
    __syncthreads();                // X in A; all reads of B done

    // ================= rnn GRU: h1 = GRU(X, h0) -> A =================
    stage_f32s(B, h0 + (size_t)base*256, 256);
    __syncthreads();
    gru<true>(A, B, rWih, rWhh, rbih, rbhh, base, hrnn);
    __syncthreads();

    // ================= 4 comm steps, fully in LDS =================
    #pragma unroll 1
    for (int step = 0; step < 4; ++step){
        comm_c(A, B, NBl, invl);    // reads A, writes c -> B
        __syncthreads();
        gru<false>(A, B, cWih, cWhh, cbih, cbhh, base, nullptr);
        __syncthreads();
    }

    // ================= q = h @ W2^T + b2 (N=16, one n-tile) =================
    if (wv < 4){
        facc4 qa = (facc4){0.f,0.f,0.f,0.f};
        int rowl = wv*16 + r16;
        const int rb = rowl*256, rx = rowl & 7;
        const unsigned short* brow = W2c + (size_t)r16*256 + q8;
        #pragma unroll
        for (int k0 = 0; k0 < 256; k0 += 32){
            int c8 = (k0 + q8) >> 3;
            frag8 af = *(const frag8*)(A + rb + ((c8 ^ rx) << 3));
            frag8 bf = *(const frag8*)(brow + k0);
            qa = mfma16(af, bf, qa);
        }
        float bias = b2[r16];
        #pragma unroll
        for (int k = 0; k < 4; ++k)
            qout[(size_t)(base + wv*16 + q4 + k)*16 + r16] = qa[k] + bias;
    }
}

extern "C" void kernel_launch(void* const* d_in, const int* in_sizes, int n_in,
                              void* d_out, int out_size, void* d_ws, size_t ws_size,
                              hipStream_t stream)
{
    const float* inputs = (const float*)d_in[0];
    const float* h0     = (const float*)d_in[1];
    const float* W1     = (const float*)d_in[2];
    const float* b1     = (const float*)d_in[3];
    const float* rWih   = (const float*)d_in[4];
    const float* rWhh   = (const float*)d_in[5];
    const float* rbih   = (const float*)d_in[6];
    const float* rbhh   = (const float*)d_in[7];
    const float* cWih   = (const float*)d_in[8];
    const float* cWhh   = (const float*)d_in[9];
    const float* cbih   = (const float*)d_in[10];
    const float* cbhh   = (const float*)d_in[11];
    const float* W2     = (const float*)d_in[12];
    const float* b2     = (const float*)d_in[13];

    float* qout = (float*)d_out;                    // 65536 x 16
    float* hrnn = qout + (size_t)65536*16;          // 65536 x 256

    // ws: bf16 weights only (921600 elems), segments packed contiguously
    unsigned short* wsb   = (unsigned short*)d_ws;
    unsigned short* W1c   = wsb;
    unsigned short* rWihc = wsb + 131072;
    unsigned short* rWhhc = wsb + 327680;
    unsigned short* cWihc = wsb + 524288;
    unsigned short* cWhhc = wsb + 720896;
    unsigned short* W2c   = wsb + 917504;

    k_prep <<<900, dim3(256), 0, stream>>>(W1, rWih, rWhh, cWih, cWhh, W2, wsb);
    k_fused<<<1024, dim3(512), 0, stream>>>(inputs, h0, W1c, b1,
                                            rWihc, rWhhc, rbih, rbhh,
                                            cWihc, cWhhc, cbih, cbhh,
                                            W2c, b2, qout, hrnn);
}

// Round 7
// 1871.602 us; speedup vs baseline: 1.8413x; 1.1528x over previous
//
#include <hip/hip_runtime.h>

// CommAgent fully-fused pipeline for MI355X (gfx950), bf16 MFMA throughout.
// ROWS=65536, INPUT=512, H=256, NA=32, 4 comm steps, N_ACTIONS=16.
//
// Round-7: spill demand removal. r2-r6 showed VGPR pinned at 128 (the
// backend's LDS-occupancy-derived budget) with 1.4-2.9 GB of scratch
// traffic: demand ~115-130 grazes the budget and the allocator spills the
// excess. This round processes the GRU per 32-row half (NMB=2 in r, z, AND
// n phases): persistent rp+zp = 16 regs, worst-phase live set ~60-70 VGPR,
// unambiguously below budget. Weights re-read per half (L2-resident).
// Structure otherwise = round 6 (512 threads, 8 waves x 32 cols, LDS ping-pong).

typedef __attribute__((ext_vector_type(8))) short frag8;   // 8 bf16 (4 VGPRs)
typedef __attribute__((ext_vector_type(4))) float facc4;   // MFMA C/D
typedef __attribute__((ext_vector_type(4))) float f32x4;   // NT-loadable float4

__device__ __forceinline__ unsigned short f2bf(float f){
    unsigned u = __builtin_bit_cast(unsigned, f);
    u += 0x7fffu + ((u >> 16) & 1u);            // RNE
    return (unsigned short)(u >> 16);
}
__device__ __forceinline__ float bf2f(unsigned short h){
    unsigned u = ((unsigned)h) << 16;
    return __builtin_bit_cast(float, u);
}
__device__ __forceinline__ unsigned pk2(float a, float b){
    return (unsigned)f2bf(a) | ((unsigned)f2bf(b) << 16);
}
__device__ __forceinline__ float sigm(float x){ return 1.0f / (1.0f + __expf(-x)); }
__device__ __forceinline__ float tanh_(float x){ return 2.0f / (1.0f + __expf(-2.0f*x)) - 1.0f; }

__device__ __forceinline__ facc4 mfma16(frag8 a, frag8 b, facc4 c){
    return __builtin_amdgcn_mfma_f32_16x16x32_bf16(a, b, c, 0, 0, 0);
}
__device__ __forceinline__ void zacc(facc4* p, int n){
    #pragma unroll
    for (int i = 0; i < 16; ++i) { if (i < n) p[i] = (facc4){0.f,0.f,0.f,0.f}; }
}
// XOR-swizzled LDS index (16B-chunk granularity), ld=256 shorts
__device__ __forceinline__ int swz(int row, int col, int ld){
    return row*ld + ((((col >> 3) ^ (row & 7)) << 3) | (col & 7));
}

// acc[NMB][NTT] += A_lds(rows mb0*16..) @ W[nrow0 + tt*16 rows, K]^T
// nrow0 already includes gate offset + wv*32.
template<int NMB, int NTT>
__device__ __forceinline__ void gemm_bt(facc4 (&acc)[NMB][NTT],
    const unsigned short* Al, const int ld, const int mb0,
    const unsigned short* __restrict__ W, const int nrow0, const int K, const int wK)
{
    const int lane = threadIdx.x & 63;
    const int r16  = lane & 15;
    const int q8   = (lane >> 4) << 3;
    int rowbase[NMB], rx[NMB];
    #pragma unroll
    for (int mb = 0; mb < NMB; ++mb){
        int row = (mb0 + mb)*16 + r16;
        rowbase[mb] = row * ld;
        rx[mb] = row & 7;
    }
    const unsigned short* wbase = W + (size_t)(nrow0 + r16) * wK + q8;
    for (int k0 = 0; k0 < K; k0 += 32){
        const int c8 = (k0 + q8) >> 3;
        frag8 a[NMB];
        #pragma unroll
        for (int mb = 0; mb < NMB; ++mb)
            a[mb] = *(const frag8*)(Al + rowbase[mb] + ((c8 ^ rx[mb]) << 3));
        #pragma unroll
        for (int tt = 0; tt < NTT; ++tt){
            frag8 b = *(const frag8*)(wbase + tt*16*wK + k0);
            #pragma unroll
            for (int mb = 0; mb < NMB; ++mb)
                acc[mb][tt] = mfma16(a[mb], b, acc[mb][tt]);
        }
    }
}

// stage 64 rows x 256 cols of f32 (row stride sld) -> swizzled bf16 LDS (ld=256)
// 512 threads; non-temporal loads (pure stream)
__device__ __forceinline__ void stage_f32s(unsigned short* dst, const float* src, int sld){
    int t = threadIdx.x;
    #pragma unroll
    for (int it = 0; it < 4; ++it){
        int idx = it*512 + t;                  // 2048 chunks of 8 shorts
        int row = idx >> 5, ch = idx & 31;
        const f32x4* s = (const f32x4*)(src + (size_t)row*sld + (ch << 3));
        f32x4 a = __builtin_nontemporal_load(s);
        f32x4 b = __builtin_nontemporal_load(s + 1);
        uint4 o; o.x = pk2(a.x,a.y); o.y = pk2(a.z,a.w); o.z = pk2(b.x,b.y); o.w = pk2(b.z,b.w);
        *(uint4*)(dst + row*256 + ((ch ^ (row & 7)) << 3)) = o;
    }
}

// ---- weight f32->bf16 conversion (segments packed contiguously in ws) ----
__global__ void k_prep(const float* __restrict__ s0, const float* __restrict__ s1,
                       const float* __restrict__ s2, const float* __restrict__ s3,
                       const float* __restrict__ s4, const float* __restrict__ s5,
                       unsigned short* __restrict__ dst)
{
    int idx = (blockIdx.x*256 + threadIdx.x) * 4;   // 921600 elems total
    const float* src;
    if      (idx < 131072) src = s0 + idx;
    else if (idx < 327680) src = s1 + (idx - 131072);
    else if (idx < 524288) src = s2 + (idx - 327680);
    else if (idx < 720896) src = s3 + (idx - 524288);
    else if (idx < 917504) src = s4 + (idx - 720896);
    else                   src = s5 + (idx - 917504);
    float4 v = *(const float4*)src;
    uint2 o; o.x = pk2(v.x, v.y); o.y = pk2(v.z, v.w);
    *(uint2*)(dst + idx) = o;
}

// ---- GRU for ONE 32-row half (m-blocks mb0=mbh*2, +1). 512 threads,
// 8 waves x 32 cols. gi from A (h written back into A), gh from B.
// Persistent across gemms: rp+zp = 16 regs only. Internal barrier
// separates this half's A-reads from its A-writes; the other half's rows
// are disjoint so no barrier is needed between halves.
template<bool WRITE_F32>
__device__ __forceinline__ void gru_half(const int mbh,
    unsigned short* A, const unsigned short* B,      // LDS, ld=256 swizzled
    const unsigned short* __restrict__ Wih, const unsigned short* __restrict__ Whh,
    const float* __restrict__ bih, const float* __restrict__ bhh,
    int base, float* __restrict__ out32)
{
    const int lane = threadIdx.x & 63, wv = threadIdx.x >> 6;
    const int r16 = lane & 15, q4 = (lane >> 4) << 2;
    const int mb0 = mbh*2;
    unsigned rp[2][2][2], zp[2][2][2];
    // phase r
    {
        facc4 acc[2][2];
        zacc(&acc[0][0], 4);
        gemm_bt<2,2>(acc, A, 256, mb0, Wih, wv*32, 256, 256);
        gemm_bt<2,2>(acc, B, 256, mb0, Whh, wv*32, 256, 256);
        #pragma unroll
        for (int tt = 0; tt < 2; ++tt){
            int col = wv*32 + tt*16 + r16;
            float bs = bih[col] + bhh[col];
            #pragma unroll
            for (int m2 = 0; m2 < 2; ++m2){
                rp[m2][tt][0] = pk2(sigm(acc[m2][tt][0]+bs), sigm(acc[m2][tt][1]+bs));
                rp[m2][tt][1] = pk2(sigm(acc[m2][tt][2]+bs), sigm(acc[m2][tt][3]+bs));
            }
        }
    }
    // phase z
    {
        facc4 acc[2][2];
        zacc(&acc[0][0], 4);
        gemm_bt<2,2>(acc, A, 256, mb0, Wih, 256 + wv*32, 256, 256);
        gemm_bt<2,2>(acc, B, 256, mb0, Whh, 256 + wv*32, 256, 256);
        #pragma unroll
        for (int tt = 0; tt < 2; ++tt){
            int col = wv*32 + tt*16 + r16;
            float bs = bih[256+col] + bhh[256+col];
            #pragma unroll
            for (int m2 = 0; m2 < 2; ++m2){
                zp[m2][tt][0] = pk2(sigm(acc[m2][tt][0]+bs), sigm(acc[m2][tt][1]+bs));
                zp[m2][tt][1] = pk2(sigm(acc[m2][tt][2]+bs), sigm(acc[m2][tt][3]+bs));
            }
        }
    }
    // phase n + fused epilogue
    {
        facc4 ai[2][2], ah[2][2];
        zacc(&ai[0][0], 4);
        zacc(&ah[0][0], 4);
        gemm_bt<2,2>(ai, A, 256, mb0, Wih, 512 + wv*32, 256, 256);
        gemm_bt<2,2>(ah, B, 256, mb0, Whh, 512 + wv*32, 256, 256);
        __syncthreads();   // all waves done reading this half's A rows
        #pragma unroll
        for (int tt = 0; tt < 2; ++tt){
            int col = wv*32 + tt*16 + r16;
            float bi = bih[512+col], bh2 = bhh[512+col];
            #pragma unroll
            for (int m2 = 0; m2 < 2; ++m2){
                int mb = mb0 + m2;
                #pragma unroll
                for (int k = 0; k < 4; ++k){
                    int rloc = mb*16 + q4 + k;
                    float iv = ai[m2][tt][k] + bi;
                    float hv = ah[m2][tt][k] + bh2;
                    float r = bf2f((unsigned short)(rp[m2][tt][k>>1] >> ((k&1)*16)));
                    float z = bf2f((unsigned short)(zp[m2][tt][k>>1] >> ((k&1)*16)));
                    float n = tanh_(iv + r*hv);
                    float hprev = bf2f(B[swz(rloc, col, 256)]);
                    float h = (1.f - z)*n + z*hprev;
                    if (WRITE_F32) out32[(size_t)(base + rloc)*256 + col] = h;
                    A[swz(rloc, col, 256)] = f2bf(h);
                }
            }
        }
    }
}

// c = (NB @ h) * invn, per 32-agent group; h in Hl (swizzled), out to Cl (swizzled)
__device__ __forceinline__ void comm_c(const unsigned short* Hl, unsigned short* Cl,
                                       const unsigned short* NBl, const float* invl)
{
    const int lane = threadIdx.x & 63, wv = threadIdx.x >> 6;
    const int r16 = lane & 15, q8 = (lane >> 4) << 3, q4 = (lane >> 4) << 2;
    facc4 acc[4][2];
    zacc(&acc[0][0], 8);
    frag8 a[4];
    #pragma unroll
    for (int mb = 0; mb < 4; ++mb)
        a[mb] = *(const frag8*)(NBl + (mb*16 + r16)*40 + q8);
    #pragma unroll
    for (int tt = 0; tt < 2; ++tt){
        int col = wv*32 + tt*16 + r16;
        int cc = col >> 3, c7 = col & 7;
        frag8 b0, b1;
        #pragma unroll
        for (int j = 0; j < 8; ++j){
            int k0r = q8 + j;          // group 0 rows 0..31
            int k1r = 32 + q8 + j;     // group 1 rows 32..63
            b0[j] = (short)Hl[k0r*256 + (((cc ^ (k0r & 7)) << 3) | c7)];
            b1[j] = (short)Hl[k1r*256 + (((cc ^ (k1r & 7)) << 3) | c7)];
        }
        acc[0][tt] = mfma16(a[0], b0, acc[0][tt]);
        acc[1][tt] = mfma16(a[1], b0, acc[1][tt]);
        acc[2][tt] = mfma16(a[2], b1, acc[2][tt]);
        acc[3][tt] = mfma16(a[3], b1, acc[3][tt]);
    }
    #pragma unroll
    for (int mb = 0; mb < 4; ++mb){
        #pragma unroll
        for (int k = 0; k < 4; ++k){
            int rloc = mb*16 + q4 + k;
            float inv = invl[rloc];
            #pragma unroll
            for (int tt = 0; tt < 2; ++tt){
                int col = wv*32 + tt*16 + r16;
                Cl[swz(rloc, col, 256)] = f2bf(acc[mb][tt][k] * inv);
            }
        }
    }
}

// ---- the whole pipeline, 64 rows (2 agent groups) per block, 512 threads ----
__global__ __launch_bounds__(512) void k_fused(
    const float* __restrict__ inputs, const float* __restrict__ h0,
    const unsigned short* __restrict__ W1c, const float* __restrict__ b1,
    const unsigned short* __restrict__ rWih, const unsigned short* __restrict__ rWhh,
    const float* __restrict__ rbih, const float* __restrict__ rbhh,
    const unsigned short* __restrict__ cWih, const unsigned short* __restrict__ cWhh,
    const float* __restrict__ cbih, const float* __restrict__ cbhh,
    const unsigned short* __restrict__ W2c, const float* __restrict__ b2,
    float* __restrict__ qout, float* __restrict__ hrnn)
{
    __shared__ unsigned short A[64*256];     // 32 KB: X, then h
    __shared__ unsigned short B[64*256];     // 32 KB: input halves, h0, then C
    __shared__ unsigned short NBl[64*40];    // 5 KB (padded ld=40 vs bank conflicts)
    __shared__ float invl[64];
    const int base = blockIdx.x * 64;
    const int lane = threadIdx.x & 63, wv = threadIdx.x >> 6;
    const int r16 = lane & 15, q8 = (lane >> 4) << 3, q4 = (lane >> 4) << 2;

    // ================= phase X: x = relu(inp @ W1^T + b1) -> A =================
    {
        facc4 acc[4][2];
        zacc(&acc[0][0], 8);
        // K-half 1 (input cols 0..255)
        stage_f32s(B, inputs + (size_t)base*512, 512);
        __syncthreads();
        gemm_bt<4,2>(acc, B, 256, 0, W1c, wv*32, 256, 512);
        __syncthreads();                            // all reads of B done
        // K-half 2 (input cols 256..511)
        stage_f32s(B, inputs + (size_t)base*512 + 256, 512);
        __syncthreads();
        // neighbor extraction: global cols 260+8k -> local col 4+8k -> chunk k, sub 4
        if (threadIdx.x < 64){
            int row = threadIdx.x;
            int gr = base + row;
            int i = gr & 31;
            int rx = row & 7;
            unsigned short* nbrow = NBl + row*40;
            float s = 0.f;
            nbrow[i] = 0;
            #pragma unroll
            for (int k = 0; k < 31; ++k){
                unsigned short v = B[row*256 + (((k ^ rx) << 3) | 4)];
                s += bf2f(v);
                nbrow[k + (k >= i)] = v;
            }
            invl[row] = 1.0f / s;
        }
        gemm_bt<4,2>(acc, B, 256, 0, W1c + 256, wv*32, 256, 512);
        // write X -> A (A not read by anyone yet)
        #pragma unroll
        for (int tt = 0; tt < 2; ++tt){
            int col = wv*32 + tt*16 + r16;
            float bias = b1[col];
            #pragma unroll
            for (int mb = 0; mb < 4; ++mb){
                #pragma unroll
                for (int k = 0; k < 4; ++k){
                    float v = fmaxf(acc[mb][tt][k] + bias, 0.f);
                    A[swz(mb*16 + q4 + k, col, 256)] = f2bf(v);
                }
            }
        }
    }
    __syncthreads();                // X in A; all reads of B done

    // ================= rnn GRU: h1 = GRU(X, h0) -> A =================
    stage_f32s(B, h0 + (size_t)base*256, 256);
    __syncthreads();
    gru_half<true>(0, A, B, rWih, rWhh, rbih, rbhh, base, hrnn);
    gru_half<true>(1, A, B, rWih, rWhh, rbih, rbhh, base, hrnn);
    __syncthreads();

    // ================= 4 comm steps, fully in LDS =================
    #pragma unroll 1
    for (int step = 0; step < 4; ++step){
        comm_c(A, B, NBl, invl);    // reads A, writes c -> B
        __syncthreads();
        gru_half<false>(0, A, B, cWih, cWhh, cbih, cbhh, base, nullptr);
        gru_half<false>(1, A, B, cWih, cWhh, cbih, cbhh, base, nullptr);
        __syncthreads();
    }

    // ================= q = h @ W2^T + b2 (N=16, one n-tile) =================
    if (wv < 4){
        facc4 qa = (facc4){0.f,0.f,0.f,0.f};
        int rowl = wv*16 + r16;
        const int rb = rowl*256, rx = rowl & 7;
        const unsigned short* brow = W2c + (size_t)r16*256 + q8;
        #pragma unroll
        for (int k0 = 0; k0 < 256; k0 += 32){
            int c8 = (k0 + q8) >> 3;
            frag8 af = *(const frag8*)(A + rb + ((c8 ^ rx) << 3));
            frag8 bf = *(const frag8*)(brow + k0);
            qa = mfma16(af, bf, qa);
        }
        float bias = b2[r16];
        #pragma unroll
        for (int k = 0; k < 4; ++k)
            qout[(size_t)(base + wv*16 + q4 + k)*16 + r16] = qa[k] + bias;
    }
}

extern "C" void kernel_launch(void* const* d_in, const int* in_sizes, int n_in,
                              void* d_out, int out_size, void* d_ws, size_t ws_size,
                              hipStream_t stream)
{
    const float* inputs = (const float*)d_in[0];
    const float* h0     = (const float*)d_in[1];
    const float* W1     = (const float*)d_in[2];
    const float* b1     = (const float*)d_in[3];
    const float* rWih   = (const float*)d_in[4];
    const float* rWhh   = (const float*)d_in[5];
    const float* rbih   = (const float*)d_in[6];
    const float* rbhh   = (const float*)d_in[7];
    const float* cWih   = (const float*)d_in[8];
    const float* cWhh   = (const float*)d_in[9];
    const float* cbih   = (const float*)d_in[10];
    const float* cbhh   = (const float*)d_in[11];
    const float* W2     = (const float*)d_in[12];
    const float* b2     = (const float*)d_in[13];

    float* qout = (float*)d_out;                    // 65536 x 16
    float* hrnn = qout + (size_t)65536*16;          // 65536 x 256

    // ws: bf16 weights only (921600 elems), segments packed contiguously
    unsigned short* wsb   = (unsigned short*)d_ws;
    unsigned short* W1c   = wsb;
    unsigned short* rWihc = wsb + 131072;
    unsigned short* rWhhc = wsb + 327680;
    unsigned short* cWihc = wsb + 524288;
    unsigned short* cWhhc = wsb + 720896;
    unsigned short* W2c   = wsb + 917504;

    k_prep <<<900, dim3(256), 0, stream>>>(W1, rWih, rWhh, cWih, cWhh, W2, wsb);
    k_fused<<<1024, dim3(512), 0, stream>>>(inputs, h0, W1c, b1,
                                            rWihc, rWhhc, rbih, rbhh,
                                            cWihc, cWhhc, cbih, cbhh,
                                            W2c, b2, qout, hrnn);
}

// Round 8
// 1262.252 us; speedup vs baseline: 2.7302x; 1.4827x over previous
//
#include <hip/hip_runtime.h>

// CommAgent fully-fused pipeline for MI355X (gfx950), bf16 MFMA throughout.
// ROWS=65536, INPUT=512, H=256, NA=32, 4 comm steps, N_ACTIONS=16.
//
// Round-8: cap the compiler's VMEM prefetch window. The gemm K-loop (8
// iters, compile-time) was fully unrolled and ALL B-fragment loads hoisted
// -> 64+ regs of in-flight loads -> live range balloons to fill the 128
// budget -> spills (the reason VGPR pinned at 128 for 5 rounds while named
// state shrank). #pragma unroll 2 bounds the window at ~32 regs.
// Plus: non-temporal hrnn/q stores so the 67 MB output stream stops
// evicting the 1.84 MB L2-resident weight set (the FETCH excess).

typedef __attribute__((ext_vector_type(8))) short frag8;   // 8 bf16 (4 VGPRs)
typedef __attribute__((ext_vector_type(4))) float facc4;   // MFMA C/D
typedef __attribute__((ext_vector_type(4))) float f32x4;   // NT-loadable float4

__device__ __forceinline__ unsigned short f2bf(float f){
    unsigned u = __builtin_bit_cast(unsigned, f);
    u += 0x7fffu + ((u >> 16) & 1u);            // RNE
    return (unsigned short)(u >> 16);
}
__device__ __forceinline__ float bf2f(unsigned short h){
    unsigned u = ((unsigned)h) << 16;
    return __builtin_bit_cast(float, u);
}
__device__ __forceinline__ unsigned pk2(float a, float b){
    return (unsigned)f2bf(a) | ((unsigned)f2bf(b) << 16);
}
__device__ __forceinline__ float sigm(float x){ return 1.0f / (1.0f + __expf(-x)); }
__device__ __forceinline__ float tanh_(float x){ return 2.0f / (1.0f + __expf(-2.0f*x)) - 1.0f; }

__device__ __forceinline__ facc4 mfma16(frag8 a, frag8 b, facc4 c){
    return __builtin_amdgcn_mfma_f32_16x16x32_bf16(a, b, c, 0, 0, 0);
}
__device__ __forceinline__ void zacc(facc4* p, int n){
    #pragma unroll
    for (int i = 0; i < 16; ++i) { if (i < n) p[i] = (facc4){0.f,0.f,0.f,0.f}; }
}
// XOR-swizzled LDS index (16B-chunk granularity), ld=256 shorts
__device__ __forceinline__ int swz(int row, int col, int ld){
    return row*ld + ((((col >> 3) ^ (row & 7)) << 3) | (col & 7));
}

// acc[NMB][NTT] += A_lds(rows mb0*16..) @ W[nrow0 + tt*16 rows, K]^T
// nrow0 already includes gate offset + wv*32.
// unroll 2: bound the VMEM prefetch window (see round-8 header comment).
template<int NMB, int NTT>
__device__ __forceinline__ void gemm_bt(facc4 (&acc)[NMB][NTT],
    const unsigned short* Al, const int ld, const int mb0,
    const unsigned short* __restrict__ W, const int nrow0, const int K, const int wK)
{
    const int lane = threadIdx.x & 63;
    const int r16  = lane & 15;
    const int q8   = (lane >> 4) << 3;
    int rowbase[NMB], rx[NMB];
    #pragma unroll
    for (int mb = 0; mb < NMB; ++mb){
        int row = (mb0 + mb)*16 + r16;
        rowbase[mb] = row * ld;
        rx[mb] = row & 7;
    }
    const unsigned short* wbase = W + (size_t)(nrow0 + r16) * wK + q8;
    #pragma unroll 2
    for (int k0 = 0; k0 < K; k0 += 32){
        const int c8 = (k0 + q8) >> 3;
        frag8 a[NMB];
        #pragma unroll
        for (int mb = 0; mb < NMB; ++mb)
            a[mb] = *(const frag8*)(Al + rowbase[mb] + ((c8 ^ rx[mb]) << 3));
        #pragma unroll
        for (int tt = 0; tt < NTT; ++tt){
            frag8 b = *(const frag8*)(wbase + tt*16*wK + k0);
            #pragma unroll
            for (int mb = 0; mb < NMB; ++mb)
                acc[mb][tt] = mfma16(a[mb], b, acc[mb][tt]);
        }
    }
}

// stage 64 rows x 256 cols of f32 (row stride sld) -> swizzled bf16 LDS (ld=256)
// 512 threads; non-temporal loads (pure stream)
__device__ __forceinline__ void stage_f32s(unsigned short* dst, const float* src, int sld){
    int t = threadIdx.x;
    #pragma unroll
    for (int it = 0; it < 4; ++it){
        int idx = it*512 + t;                  // 2048 chunks of 8 shorts
        int row = idx >> 5, ch = idx & 31;
        const f32x4* s = (const f32x4*)(src + (size_t)row*sld + (ch << 3));
        f32x4 a = __builtin_nontemporal_load(s);
        f32x4 b = __builtin_nontemporal_load(s + 1);
        uint4 o; o.x = pk2(a.x,a.y); o.y = pk2(a.z,a.w); o.z = pk2(b.x,b.y); o.w = pk2(b.z,b.w);
        *(uint4*)(dst + row*256 + ((ch ^ (row & 7)) << 3)) = o;
    }
}

// ---- weight f32->bf16 conversion (segments packed contiguously in ws) ----
__global__ void k_prep(const float* __restrict__ s0, const float* __restrict__ s1,
                       const float* __restrict__ s2, const float* __restrict__ s3,
                       const float* __restrict__ s4, const float* __restrict__ s5,
                       unsigned short* __restrict__ dst)
{
    int idx = (blockIdx.x*256 + threadIdx.x) * 4;   // 921600 elems total
    const float* src;
    if      (idx < 131072) src = s0 + idx;
    else if (idx < 327680) src = s1 + (idx - 131072);
    else if (idx < 524288) src = s2 + (idx - 327680);
    else if (idx < 720896) src = s3 + (idx - 524288);
    else if (idx < 917504) src = s4 + (idx - 720896);
    else                   src = s5 + (idx - 917504);
    float4 v = *(const float4*)src;
    uint2 o; o.x = pk2(v.x, v.y); o.y = pk2(v.z, v.w);
    *(uint2*)(dst + idx) = o;
}

// ---- GRU for ONE 32-row half (m-blocks mb0=mbh*2, +1). 512 threads,
// 8 waves x 32 cols. gi from A (h written back into A), gh from B.
// Persistent across gemms: rp+zp = 16 regs only.
template<bool WRITE_F32>
__device__ __forceinline__ void gru_half(const int mbh,
    unsigned short* A, const unsigned short* B,      // LDS, ld=256 swizzled
    const unsigned short* __restrict__ Wih, const unsigned short* __restrict__ Whh,
    const float* __restrict__ bih, const float* __restrict__ bhh,
    int base, float* __restrict__ out32)
{
    const int lane = threadIdx.x & 63, wv = threadIdx.x >> 6;
    const int r16 = lane & 15, q4 = (lane >> 4) << 2;
    const int mb0 = mbh*2;
    unsigned rp[2][2][2], zp[2][2][2];
    // phase r
    {
        facc4 acc[2][2];
        zacc(&acc[0][0], 4);
        gemm_bt<2,2>(acc, A, 256, mb0, Wih, wv*32, 256, 256);
        gemm_bt<2,2>(acc, B, 256, mb0, Whh, wv*32, 256, 256);
        #pragma unroll
        for (int tt = 0; tt < 2; ++tt){
            int col = wv*32 + tt*16 + r16;
            float bs = bih[col] + bhh[col];
            #pragma unroll
            for (int m2 = 0; m2 < 2; ++m2){
                rp[m2][tt][0] = pk2(sigm(acc[m2][tt][0]+bs), sigm(acc[m2][tt][1]+bs));
                rp[m2][tt][1] = pk2(sigm(acc[m2][tt][2]+bs), sigm(acc[m2][tt][3]+bs));
            }
        }
    }
    // phase z
    {
        facc4 acc[2][2];
        zacc(&acc[0][0], 4);
        gemm_bt<2,2>(acc, A, 256, mb0, Wih, 256 + wv*32, 256, 256);
        gemm_bt<2,2>(acc, B, 256, mb0, Whh, 256 + wv*32, 256, 256);
        #pragma unroll
        for (int tt = 0; tt < 2; ++tt){
            int col = wv*32 + tt*16 + r16;
            float bs = bih[256+col] + bhh[256+col];
            #pragma unroll
            for (int m2 = 0; m2 < 2; ++m2){
                zp[m2][tt][0] = pk2(sigm(acc[m2][tt][0]+bs), sigm(acc[m2][tt][1]+bs));
                zp[m2][tt][1] = pk2(sigm(acc[m2][tt][2]+bs), sigm(acc[m2][tt][3]+bs));
            }
        }
    }
    // phase n + fused epilogue
    {
        facc4 ai[2][2], ah[2][2];
        zacc(&ai[0][0], 4);
        zacc(&ah[0][0], 4);
        gemm_bt<2,2>(ai, A, 256, mb0, Wih, 512 + wv*32, 256, 256);
        gemm_bt<2,2>(ah, B, 256, mb0, Whh, 512 + wv*32, 256, 256);
        __syncthreads();   // all waves done reading this half's A rows
        #pragma unroll
        for (int tt = 0; tt < 2; ++tt){
            int col = wv*32 + tt*16 + r16;
            float bi = bih[512+col], bh2 = bhh[512+col];
            #pragma unroll
            for (int m2 = 0; m2 < 2; ++m2){
                int mb = mb0 + m2;
                #pragma unroll
                for (int k = 0; k < 4; ++k){
                    int rloc = mb*16 + q4 + k;
                    float iv = ai[m2][tt][k] + bi;
                    float hv = ah[m2][tt][k] + bh2;
                    float r = bf2f((unsigned short)(rp[m2][tt][k>>1] >> ((k&1)*16)));
                    float z = bf2f((unsigned short)(zp[m2][tt][k>>1] >> ((k&1)*16)));
                    float n = tanh_(iv + r*hv);
                    float hprev = bf2f(B[swz(rloc, col, 256)]);
                    float h = (1.f - z)*n + z*hprev;
                    if (WRITE_F32)
                        __builtin_nontemporal_store(h, &out32[(size_t)(base + rloc)*256 + col]);
                    A[swz(rloc, col, 256)] = f2bf(h);
                }
            }
        }
    }
}

// c = (NB @ h) * invn, per 32-agent group; h in Hl (swizzled), out to Cl (swizzled)
__device__ __forceinline__ void comm_c(const unsigned short* Hl, unsigned short* Cl,
                                       const unsigned short* NBl, const float* invl)
{
    const int lane = threadIdx.x & 63, wv = threadIdx.x >> 6;
    const int r16 = lane & 15, q8 = (lane >> 4) << 3, q4 = (lane >> 4) << 2;
    facc4 acc[4][2];
    zacc(&acc[0][0], 8);
    frag8 a[4];
    #pragma unroll
    for (int mb = 0; mb < 4; ++mb)
        a[mb] = *(const frag8*)(NBl + (mb*16 + r16)*40 + q8);
    #pragma unroll
    for (int tt = 0; tt < 2; ++tt){
        int col = wv*32 + tt*16 + r16;
        int cc = col >> 3, c7 = col & 7;
        frag8 b0, b1;
        #pragma unroll
        for (int j = 0; j < 8; ++j){
            int k0r = q8 + j;          // group 0 rows 0..31
            int k1r = 32 + q8 + j;     // group 1 rows 32..63
            b0[j] = (short)Hl[k0r*256 + (((cc ^ (k0r & 7)) << 3) | c7)];
            b1[j] = (short)Hl[k1r*256 + (((cc ^ (k1r & 7)) << 3) | c7)];
        }
        acc[0][tt] = mfma16(a[0], b0, acc[0][tt]);
        acc[1][tt] = mfma16(a[1], b0, acc[1][tt]);
        acc[2][tt] = mfma16(a[2], b1, acc[2][tt]);
        acc[3][tt] = mfma16(a[3], b1, acc[3][tt]);
    }
    #pragma unroll
    for (int mb = 0; mb < 4; ++mb){
        #pragma unroll
        for (int k = 0; k < 4; ++k){
            int rloc = mb*16 + q4 + k;
            float inv = invl[rloc];
            #pragma unroll
            for (int tt = 0; tt < 2; ++tt){
                int col = wv*32 + tt*16 + r16;
                Cl[swz(rloc, col, 256)] = f2bf(acc[mb][tt][k] * inv);
            }
        }
    }
}

// ---- the whole pipeline, 64 rows (2 agent groups) per block, 512 threads ----
__global__ __launch_bounds__(512) void k_fused(
    const float* __restrict__ inputs, const float* __restrict__ h0,
    const unsigned short* __restrict__ W1c, const float* __restrict__ b1,
    const unsigned short* __restrict__ rWih, const unsigned short* __restrict__ rWhh,
    const float* __restrict__ rbih, const float* __restrict__ rbhh,
    const unsigned short* __restrict__ cWih, const unsigned short* __restrict__ cWhh,
    const float* __restrict__ cbih, const float* __restrict__ cbhh,
    const unsigned short* __restrict__ W2c, const float* __restrict__ b2,
    float* __restrict__ qout, float* __restrict__ hrnn)
{
    __shared__ unsigned short A[64*256];     // 32 KB: X, then h
    __shared__ unsigned short B[64*256];     // 32 KB: input halves, h0, then C
    __shared__ unsigned short NBl[64*40];    // 5 KB (padded ld=40 vs bank conflicts)
    __shared__ float invl[64];
    const int base = blockIdx.x * 64;
    const int lane = threadIdx.x & 63, wv = threadIdx.x >> 6;
    const int r16 = lane & 15, q8 = (lane >> 4) << 3, q4 = (lane >> 4) << 2;

    // ================= phase X: x = relu(inp @ W1^T + b1) -> A =================
    {
        facc4 acc[4][2];
        zacc(&acc[0][0], 8);
        // K-half 1 (input cols 0..255)
        stage_f32s(B, inputs + (size_t)base*512, 512);
        __syncthreads();
        gemm_bt<4,2>(acc, B, 256, 0, W1c, wv*32, 256, 512);
        __syncthreads();                            // all reads of B done
        // K-half 2 (input cols 256..511)
        stage_f32s(B, inputs + (size_t)base*512 + 256, 512);
        __syncthreads();
        // neighbor extraction: global cols 260+8k -> local col 4+8k -> chunk k, sub 4
        if (threadIdx.x < 64){
            int row = threadIdx.x;
            int gr = base + row;
            int i = gr & 31;
            int rx = row & 7;
            unsigned short* nbrow = NBl + row*40;
            float s = 0.f;
            nbrow[i] = 0;
            #pragma unroll
            for (int k = 0; k < 31; ++k){
                unsigned short v = B[row*256 + (((k ^ rx) << 3) | 4)];
                s += bf2f(v);
                nbrow[k + (k >= i)] = v;
            }
            invl[row] = 1.0f / s;
        }
        gemm_bt<4,2>(acc, B, 256, 0, W1c + 256, wv*32, 256, 512);
        // write X -> A (A not read by anyone yet)
        #pragma unroll
        for (int tt = 0; tt < 2; ++tt){
            int col = wv*32 + tt*16 + r16;
            float bias = b1[col];
            #pragma unroll
            for (int mb = 0; mb < 4; ++mb){
                #pragma unroll
                for (int k = 0; k < 4; ++k){
                    float v = fmaxf(acc[mb][tt][k] + bias, 0.f);
                    A[swz(mb*16 + q4 + k, col, 256)] = f2bf(v);
                }
            }
        }
    }
    __syncthreads();                // X in A; all reads of B done

    // ================= rnn GRU: h1 = GRU(X, h0) -> A =================
    stage_f32s(B, h0 + (size_t)base*256, 256);
    __syncthreads();
    gru_half<true>(0, A, B, rWih, rWhh, rbih, rbhh, base, hrnn);
    gru_half<true>(1, A, B, rWih, rWhh, rbih, rbhh, base, hrnn);
    __syncthreads();

    // ================= 4 comm steps, fully in LDS =================
    #pragma unroll 1
    for (int step = 0; step < 4; ++step){
        comm_c(A, B, NBl, invl);    // reads A, writes c -> B
        __syncthreads();
        gru_half<false>(0, A, B, cWih, cWhh, cbih, cbhh, base, nullptr);
        gru_half<false>(1, A, B, cWih, cWhh, cbih, cbhh, base, nullptr);
        __syncthreads();
    }

    // ================= q = h @ W2^T + b2 (N=16, one n-tile) =================
    if (wv < 4){
        facc4 qa = (facc4){0.f,0.f,0.f,0.f};
        int rowl = wv*16 + r16;
        const int rb = rowl*256, rx = rowl & 7;
        const unsigned short* brow = W2c + (size_t)r16*256 + q8;
        #pragma unroll
        for (int k0 = 0; k0 < 256; k0 += 32){
            int c8 = (k0 + q8) >> 3;
            frag8 af = *(const frag8*)(A + rb + ((c8 ^ rx) << 3));
            frag8 bf = *(const frag8*)(brow + k0);
            qa = mfma16(af, bf, qa);
        }
        float bias = b2[r16];
        #pragma unroll
        for (int k = 0; k < 4; ++k)
            __builtin_nontemporal_store(qa[k] + bias,
                &qout[(size_t)(base + wv*16 + q4 + k)*16 + r16]);
    }
}

extern "C" void kernel_launch(void* const* d_in, const int* in_sizes, int n_in,
                              void* d_out, int out_size, void* d_ws, size_t ws_size,
                              hipStream_t stream)
{
    const float* inputs = (const float*)d_in[0];
    const float* h0     = (const float*)d_in[1];
    const float* W1     = (const float*)d_in[2];
    const float* b1     = (const float*)d_in[3];
    const float* rWih   = (const float*)d_in[4];
    const float* rWhh   = (const float*)d_in[5];
    const float* rbih   = (const float*)d_in[6];
    const float* rbhh   = (const float*)d_in[7];
    const float* cWih   = (const float*)d_in[8];
    const float* cWhh   = (const float*)d_in[9];
    const float* cbih   = (const float*)d_in[10];
    const float* cbhh   = (const float*)d_in[11];
    const float* W2     = (const float*)d_in[12];
    const float* b2     = (const float*)d_in[13];

    float* qout = (float*)d_out;                    // 65536 x 16
    float* hrnn = qout + (size_t)65536*16;          // 65536 x 256

    // ws: bf16 weights only (921600 elems), segments packed contiguously
    unsigned short* wsb   = (unsigned short*)d_ws;
    unsigned short* W1c   = wsb;
    unsigned short* rWihc = wsb + 131072;
    unsigned short* rWhhc = wsb + 327680;
    unsigned short* cWihc = wsb + 524288;
    unsigned short* cWhhc = wsb + 720896;
    unsigned short* W2c   = wsb + 917504;

    k_prep <<<900, dim3(256), 0, stream>>>(W1, rWih, rWhh, cWih, cWhh, W2, wsb);
    k_fused<<<1024, dim3(512), 0, stream>>>(inputs, h0, W1c, b1,
                                            rWihc, rWhhc, rbih, rbhh,
                                            cWihc, cWhhc, cbih, cbhh,
                                            W2c, b2, qout, hrnn);
}